// Round 1
// baseline (505.763 us; speedup 1.0000x reference)
//
#include <hip/hip_runtime.h>
#include <hip/hip_bf16.h>

// GraphSAGE 2-layer forward, fp32.
// Pipeline: CSR build (deg -> scan -> fill) ; agg1 (mean of x[src]) -> cat1=[agg|x]
//           g1: h1 = relu(cat1 @ B1cat + b1)
//           g2a: t2 (=d_out scratch) = h1 @ W2l^T
//           agg2: agg2 = mean of t2[src]   (aggregate AFTER transform: 64-dim not 256-dim)
//           g2b: out = h1 @ W2r^T + b2 + agg2

#define N_NODES 50000
#define N_EDGES 800000
#define DIM_IN 128
#define DIM_H 256
#define DIM_OUT 64

// ---------------- CSR build ----------------

__global__ void deg_count_kernel(const int* __restrict__ ei, int* __restrict__ deg) {
    int e = blockIdx.x * 256 + threadIdx.x;
    if (e < N_EDGES) atomicAdd(&deg[ei[N_EDGES + e]], 1);
}

__global__ __launch_bounds__(1024) void scan_kernel(const int* __restrict__ deg,
                                                    int* __restrict__ row_start) {
    __shared__ int wsum[16];
    __shared__ int carry_s;
    const int tid = threadIdx.x, lane = tid & 63, wid = tid >> 6;
    if (tid == 0) carry_s = 0;
    __syncthreads();
    for (int base = 0; base < N_NODES; base += 1024) {
        int i = base + tid;
        int v = (i < N_NODES) ? deg[i] : 0;
        int sc = v;
        #pragma unroll
        for (int off = 1; off < 64; off <<= 1) {
            int t = __shfl_up(sc, off);
            if (lane >= off) sc += t;
        }
        if (lane == 63) wsum[wid] = sc;
        __syncthreads();
        if (wid == 0) {
            int ws = (lane < 16) ? wsum[lane] : 0;
            #pragma unroll
            for (int off = 1; off < 16; off <<= 1) {
                int t = __shfl_up(ws, off);
                if (lane >= off) ws += t;
            }
            if (lane < 16) wsum[lane] = ws;  // inclusive scan of wave sums
        }
        __syncthreads();
        int wave_off = (wid > 0) ? wsum[wid - 1] : 0;
        if (i < N_NODES) row_start[i] = carry_s + wave_off + sc - v;  // exclusive
        __syncthreads();  // everyone has read carry_s/wsum
        if (tid == 1023) carry_s += wsum[15];
        __syncthreads();
    }
}

__global__ void fill_kernel(const int* __restrict__ ei, const int* __restrict__ row_start,
                            int* __restrict__ cursor, int* __restrict__ csr) {
    int e = blockIdx.x * 256 + threadIdx.x;
    if (e >= N_EDGES) return;
    int d = ei[N_EDGES + e];
    int pos = atomicAdd(&cursor[d], 1);
    csr[row_start[d] + pos] = ei[e];
}

__global__ void invdeg_kernel(const int* __restrict__ deg, float* __restrict__ inv) {
    int n = blockIdx.x * 256 + threadIdx.x;
    if (n < N_NODES) inv[n] = 1.0f / fmaxf((float)deg[n], 1.0f);
}

// ---------------- weight transpose: out[c*N + j] = in[j*K + c] ----------------

__global__ void transpose_kernel(const float* __restrict__ in, float* __restrict__ out,
                                 int K, int N) {
    int idx = blockIdx.x * 256 + threadIdx.x;
    if (idx >= K * N) return;
    int c = idx / N, j = idx - c * N;
    out[idx] = in[j * K + c];
}

// ---------------- aggregation (1 wave per node) ----------------

// cat1[n] = [ mean_{src->n} x[src] (128) | x[n] (128) ]
__global__ void agg1_kernel(const int* __restrict__ rs, const int* __restrict__ deg,
                            const int* __restrict__ csr, const float* __restrict__ x,
                            const float* __restrict__ inv_deg, float* __restrict__ cat1) {
    const int wid = threadIdx.x >> 6, lane = threadIdx.x & 63;
    const int n = blockIdx.x * (blockDim.x >> 6) + wid;
    if (n >= N_NODES) return;
    const int beg = rs[n], cnt = deg[n];
    float sx = 0.f, sy = 0.f;
    for (int i0 = 0; i0 < cnt; i0 += 64) {
        int m = cnt - i0; if (m > 64) m = 64;
        int idx = (lane < m) ? csr[beg + i0 + lane] : 0;
        for (int i = 0; i < m; ++i) {
            int s = __shfl(idx, i);
            float2 v = ((const float2*)(x + (size_t)s * DIM_IN))[lane];
            sx += v.x; sy += v.y;
        }
    }
    float w = inv_deg[n];
    float2* row = (float2*)(cat1 + (size_t)n * (2 * DIM_IN));
    row[lane] = make_float2(sx * w, sy * w);
    row[64 + lane] = ((const float2*)(x + (size_t)n * DIM_IN))[lane];
}

// agg2[n] = mean_{src->n} t2[src]  (64-dim)
__global__ void agg2_kernel(const int* __restrict__ rs, const int* __restrict__ deg,
                            const int* __restrict__ csr, const float* __restrict__ t2,
                            const float* __restrict__ inv_deg, float* __restrict__ agg2) {
    const int wid = threadIdx.x >> 6, lane = threadIdx.x & 63;
    const int n = blockIdx.x * (blockDim.x >> 6) + wid;
    if (n >= N_NODES) return;
    const int beg = rs[n], cnt = deg[n];
    float s = 0.f;
    for (int i0 = 0; i0 < cnt; i0 += 64) {
        int m = cnt - i0; if (m > 64) m = 64;
        int idx = (lane < m) ? csr[beg + i0 + lane] : 0;
        for (int i = 0; i < m; ++i) {
            int src = __shfl(idx, i);
            s += t2[(size_t)src * DIM_OUT + lane];
        }
    }
    agg2[(size_t)n * DIM_OUT + lane] = s * inv_deg[n];
}

// ---------------- fp32 tiled GEMM: C[M,N] = A[M,K] @ Bt[K,N] (+bias +add, relu) ----------------
// BM=BN=64, BK=32, 256 threads, 4x4 per thread.

__global__ __launch_bounds__(256) void gemm_kernel(
    const float* __restrict__ A, const float* __restrict__ Bt,
    const float* __restrict__ bias, const float* __restrict__ add,
    float* __restrict__ C, int M, int N, int K, int do_relu) {
    __shared__ float As[32][68];  // A^T tile: As[k][m]
    __shared__ float Bs[32][68];  // Bs[k][n]
    const int tid = threadIdx.x;
    const int tx = tid & 15, ty = tid >> 4;
    const int bm = blockIdx.y << 6;
    const int bn = blockIdx.x << 6;
    const int arow = tid >> 3;            // 0..31
    const int ak4 = (tid & 7) << 2;       // 0..28
    const int bk = tid >> 4;              // 0..15
    const int bn4 = (tid & 15) << 2;      // 0..60
    float acc[4][4] = {};
    for (int k0 = 0; k0 < K; k0 += 32) {
        #pragma unroll
        for (int h = 0; h < 2; ++h) {
            int m = arow + h * 32;
            int row = bm + m;
            float4 v = make_float4(0.f, 0.f, 0.f, 0.f);
            if (row < M) v = *(const float4*)(A + (size_t)row * K + k0 + ak4);
            As[ak4 + 0][m] = v.x; As[ak4 + 1][m] = v.y;
            As[ak4 + 2][m] = v.z; As[ak4 + 3][m] = v.w;
        }
        #pragma unroll
        for (int h = 0; h < 2; ++h) {
            int k = bk + h * 16;
            *(float4*)&Bs[k][bn4] = *(const float4*)(Bt + (size_t)(k0 + k) * N + bn + bn4);
        }
        __syncthreads();
        #pragma unroll
        for (int k = 0; k < 32; ++k) {
            float4 a = *(const float4*)&As[k][ty << 2];
            float4 b = *(const float4*)&Bs[k][tx << 2];
            float av[4] = {a.x, a.y, a.z, a.w};
            float bv[4] = {b.x, b.y, b.z, b.w};
            #pragma unroll
            for (int i = 0; i < 4; ++i)
                #pragma unroll
                for (int j = 0; j < 4; ++j)
                    acc[i][j] += av[i] * bv[j];
        }
        __syncthreads();
    }
    const int col = bn + (tx << 2);
    #pragma unroll
    for (int i = 0; i < 4; ++i) {
        int row = bm + (ty << 2) + i;
        if (row >= M) break;
        float r0 = acc[i][0], r1 = acc[i][1], r2 = acc[i][2], r3 = acc[i][3];
        if (bias) { r0 += bias[col]; r1 += bias[col + 1]; r2 += bias[col + 2]; r3 += bias[col + 3]; }
        if (add) {
            float4 ad = *(const float4*)(add + (size_t)row * N + col);
            r0 += ad.x; r1 += ad.y; r2 += ad.z; r3 += ad.w;
        }
        if (do_relu) { r0 = fmaxf(r0, 0.f); r1 = fmaxf(r1, 0.f); r2 = fmaxf(r2, 0.f); r3 = fmaxf(r3, 0.f); }
        float4 o; o.x = r0; o.y = r1; o.z = r2; o.w = r3;
        *(float4*)(C + (size_t)row * N + col) = o;
    }
}

// ---------------- launch ----------------

extern "C" void kernel_launch(void* const* d_in, const int* in_sizes, int n_in,
                              void* d_out, int out_size, void* d_ws, size_t ws_size,
                              hipStream_t stream) {
    const float* x   = (const float*)d_in[0];
    const int*   ei  = (const int*)d_in[1];   // [2, E]: src then dst
    const float* W1l = (const float*)d_in[2];
    const float* W1r = (const float*)d_in[3];
    const float* b1  = (const float*)d_in[4];
    const float* W2l = (const float*)d_in[5];
    const float* W2r = (const float*)d_in[6];
    const float* b2  = (const float*)d_in[7];
    float* out = (float*)d_out;

    float* ws = (float*)d_ws;
    size_t o = 0;
    int*   deg_i     = (int*)(ws + o); o += 50048;
    int*   cursor    = (int*)(ws + o); o += 50048;
    int*   row_start = (int*)(ws + o); o += 50048;
    float* inv_deg   = ws + o;         o += 50048;
    int*   csr       = (int*)(ws + o); o += 800000;
    float* cat1      = ws + o;         o += (size_t)N_NODES * 256;   // [agg1 | x]
    float* h1        = ws + o;         o += (size_t)N_NODES * 256;
    float* agg2      = ws + o;         o += (size_t)N_NODES * 64;
    float* B1cat     = ws + o;         o += 256 * 256;  // [W1l^T ; W1r^T] as [K=256][N=256]
    float* B2l       = ws + o;         o += 256 * 64;
    float* B2r       = ws + o;         o += 256 * 64;
    float* t2        = out;            // d_out doubles as t2 scratch (same size)

    hipMemsetAsync(deg_i, 0, N_NODES * sizeof(int), stream);
    hipMemsetAsync(cursor, 0, N_NODES * sizeof(int), stream);

    // weight transposes (tiny)
    transpose_kernel<<<(128 * 256 + 255) / 256, 256, 0, stream>>>(W1l, B1cat, 128, 256);
    transpose_kernel<<<(128 * 256 + 255) / 256, 256, 0, stream>>>(W1r, B1cat + 128 * 256, 128, 256);
    transpose_kernel<<<(256 * 64 + 255) / 256, 256, 0, stream>>>(W2l, B2l, 256, 64);
    transpose_kernel<<<(256 * 64 + 255) / 256, 256, 0, stream>>>(W2r, B2r, 256, 64);

    // CSR build
    deg_count_kernel<<<(N_EDGES + 255) / 256, 256, 0, stream>>>(ei, deg_i);
    scan_kernel<<<1, 1024, 0, stream>>>(deg_i, row_start);
    fill_kernel<<<(N_EDGES + 255) / 256, 256, 0, stream>>>(ei, row_start, cursor, csr);
    invdeg_kernel<<<(N_NODES + 255) / 256, 256, 0, stream>>>(deg_i, inv_deg);

    // layer 1
    agg1_kernel<<<(N_NODES + 3) / 4, 256, 0, stream>>>(row_start, deg_i, csr, x, inv_deg, cat1);
    {
        dim3 grid(256 / 64, (N_NODES + 63) / 64);
        gemm_kernel<<<grid, 256, 0, stream>>>(cat1, B1cat, b1, nullptr, h1,
                                              N_NODES, 256, 256, 1);
    }

    // layer 2: transform-then-aggregate (64-dim edge traffic instead of 256)
    {
        dim3 grid(64 / 64, (N_NODES + 63) / 64);
        gemm_kernel<<<grid, 256, 0, stream>>>(h1, B2l, nullptr, nullptr, t2,
                                              N_NODES, 64, 256, 0);
    }
    agg2_kernel<<<(N_NODES + 3) / 4, 256, 0, stream>>>(row_start, deg_i, csr, t2, inv_deg, agg2);
    {
        dim3 grid(64 / 64, (N_NODES + 63) / 64);
        gemm_kernel<<<grid, 256, 0, stream>>>(h1, B2r, b2, agg2, out,
                                              N_NODES, 64, 256, 0);
    }
}

// Round 2
// 327.280 us; speedup vs baseline: 1.5454x; 1.5454x over previous
//
#include <hip/hip_runtime.h>
#include <hip/hip_bf16.h>

// GraphSAGE 2-layer forward, bf16-MFMA inner pipeline, fp32 edges where cheap.
// Pipeline:
//   convert_x: x -> xb (bf16)
//   prep_w:    B1 = [W1l|W1r] as [256n][256k] bf16 ; B2 = [W2l;W2r] as [128n][256k] bf16
//   CSR build: deg -> 3-phase scan -> fill (+invdeg)
//   agg1:      cat1[n] = [ mean xb[src] | xb[n] ]  (bf16, [50048][256], padded rows poison)
//   gemm1:     h1 = relu(cat1 @ B1^T + b1)  (bf16, MFMA 16x16x32)
//   gemm2:     t2 = h1 @ W2l^T (bf16) ; u2 = h1 @ W2r^T (fp32)   one N=128 GEMM
//   final:     out[n] = u2[n] + b2 + invdeg[n] * sum t2[src]     (fp32 out)

#define N_NODES 50000
#define N_EDGES 800000
#define M_PAD   50048   // 391 * 128

typedef unsigned int uint;
typedef unsigned short ushort;
typedef __attribute__((ext_vector_type(8))) short short8;
typedef __attribute__((ext_vector_type(4))) float floatx4;

__device__ __forceinline__ ushort f2bf(float f) {
    union { float f; uint u; } c; c.f = f;
    uint u = c.u;
    return (ushort)((u + 0x7FFFu + ((u >> 16) & 1u)) >> 16);  // RNE
}
__device__ __forceinline__ float bf2f(ushort h) {
    union { uint u; float f; } c; c.u = ((uint)h) << 16;
    return c.f;
}
__device__ __forceinline__ void gload_lds16(const ushort* g, ushort* l) {
    __builtin_amdgcn_global_load_lds(
        (const __attribute__((address_space(1))) void*)g,
        (__attribute__((address_space(3))) void*)l, 16, 0, 0);
}

// ---------------- dtype prep ----------------

__global__ void convert_x_k(const float2* __restrict__ x2, uint* __restrict__ xb) {
    int i = blockIdx.x * 256 + threadIdx.x;
    if (i >= N_NODES * 64) return;
    float2 v = x2[i];
    xb[i] = (uint)f2bf(v.x) | ((uint)f2bf(v.y) << 16);
}

__global__ void prep_w_k(const float* __restrict__ W1l, const float* __restrict__ W1r,
                         const float* __restrict__ W2l, const float* __restrict__ W2r,
                         ushort* __restrict__ B1, ushort* __restrict__ B2) {
    int t = blockIdx.x * 256 + threadIdx.x;
    if (t < 65536) {                       // B1[n][k], n<256, k<256
        int n = t >> 8, k = t & 255;
        float v = (k < 128) ? W1l[n * 128 + k] : W1r[n * 128 + (k - 128)];
        B1[t] = f2bf(v);
    } else if (t < 98304) {                // B2[n][k], n<128, k<256
        int t2 = t - 65536;
        int n = t2 >> 8, k = t2 & 255;
        float v = (n < 64) ? W2l[n * 256 + k] : W2r[(n - 64) * 256 + k];
        B2[t2] = f2bf(v);
    }
}

// ---------------- CSR build ----------------

__global__ void deg_count_k(const int* __restrict__ ei, int* __restrict__ deg) {
    int e = blockIdx.x * 256 + threadIdx.x;
    if (e < N_EDGES) atomicAdd(&deg[ei[N_EDGES + e]], 1);
}

__global__ __launch_bounds__(1024) void scan_block_k(const int* __restrict__ deg,
                                                     int* __restrict__ rs,
                                                     int* __restrict__ bsums) {
    __shared__ int wsum[16];
    const int tid = threadIdx.x, lane = tid & 63, wid = tid >> 6;
    int i = blockIdx.x * 1024 + tid;
    int v = (i < N_NODES) ? deg[i] : 0;
    int sc = v;
    #pragma unroll
    for (int off = 1; off < 64; off <<= 1) {
        int t = __shfl_up(sc, off);
        if (lane >= off) sc += t;
    }
    if (lane == 63) wsum[wid] = sc;
    __syncthreads();
    if (wid == 0) {
        int ws = (lane < 16) ? wsum[lane] : 0;
        #pragma unroll
        for (int off = 1; off < 16; off <<= 1) {
            int t = __shfl_up(ws, off);
            if (lane >= off) ws += t;
        }
        if (lane < 16) wsum[lane] = ws;
    }
    __syncthreads();
    int woff = wid ? wsum[wid - 1] : 0;
    if (i < N_NODES) rs[i] = woff + sc - v;          // block-local exclusive
    if (tid == 1023) bsums[blockIdx.x] = wsum[15];
}

__global__ void scan_sums_k(int* __restrict__ bsums) {   // 49 sums -> exclusive, 1 wave
    int lane = threadIdx.x;
    int v = (lane < 49) ? bsums[lane] : 0;
    int sc = v;
    #pragma unroll
    for (int off = 1; off < 64; off <<= 1) {
        int t = __shfl_up(sc, off);
        if (lane >= off) sc += t;
    }
    if (lane < 49) bsums[lane] = sc - v;
}

__global__ __launch_bounds__(1024) void scan_add_inv_k(const int* __restrict__ deg,
                                                       int* __restrict__ rs,
                                                       const int* __restrict__ bsums,
                                                       float* __restrict__ inv) {
    int i = blockIdx.x * 1024 + threadIdx.x;
    if (i < N_NODES) {
        rs[i] += bsums[blockIdx.x];
        inv[i] = 1.0f / fmaxf((float)deg[i], 1.0f);
    }
}

__global__ void fill_k(const int* __restrict__ ei, const int* __restrict__ rs,
                       int* __restrict__ cursor, int* __restrict__ csr) {
    int e = blockIdx.x * 256 + threadIdx.x;
    if (e >= N_EDGES) return;
    int d = ei[N_EDGES + e];
    int pos = atomicAdd(&cursor[d], 1);
    csr[rs[d] + pos] = ei[e];
}

// ---------------- aggregation ----------------

// cat1 rows as uint (2 bf16): [agg (64 uints) | root copy (64 uints)]
__global__ void agg1_k(const int* __restrict__ rs, const int* __restrict__ deg,
                       const int* __restrict__ csr, const uint* __restrict__ xb,
                       const float* __restrict__ inv, uint* __restrict__ cat1) {
    const int wid = threadIdx.x >> 6, lane = threadIdx.x & 63;
    const int n = blockIdx.x * 4 + wid;
    if (n >= N_NODES) return;
    const int beg = rs[n], cnt = deg[n];
    float sx = 0.f, sy = 0.f;
    for (int i0 = 0; i0 < cnt; i0 += 64) {
        int m = cnt - i0; if (m > 64) m = 64;
        int idx = (lane < m) ? csr[beg + i0 + lane] : 0;
        for (int i = 0; i < m; ++i) {
            int s = __shfl(idx, i);
            uint v = xb[(size_t)s * 64 + lane];
            sx += bf2f((ushort)(v & 0xffffu));
            sy += bf2f((ushort)(v >> 16));
        }
    }
    float w = inv[n];
    cat1[(size_t)n * 128 + lane] = (uint)f2bf(sx * w) | ((uint)f2bf(sy * w) << 16);
    cat1[(size_t)n * 128 + 64 + lane] = xb[(size_t)n * 64 + lane];
}

// out[n] = u2[n] + b2 + invdeg * sum t2[src]
__global__ void final_k(const int* __restrict__ rs, const int* __restrict__ deg,
                        const int* __restrict__ csr, const ushort* __restrict__ t2,
                        const float* __restrict__ u2, const float* __restrict__ b2,
                        const float* __restrict__ inv, float* __restrict__ out) {
    const int wid = threadIdx.x >> 6, lane = threadIdx.x & 63;
    const int n = blockIdx.x * 4 + wid;
    if (n >= N_NODES) return;
    const int beg = rs[n], cnt = deg[n];
    float s = 0.f;
    for (int i0 = 0; i0 < cnt; i0 += 64) {
        int m = cnt - i0; if (m > 64) m = 64;
        int idx = (lane < m) ? csr[beg + i0 + lane] : 0;
        for (int i = 0; i < m; ++i) {
            int src = __shfl(idx, i);
            s += bf2f(t2[(size_t)src * 64 + lane]);
        }
    }
    out[(size_t)n * 64 + lane] = u2[(size_t)n * 64 + lane] + b2[lane] + s * inv[n];
}

// ---------------- bf16 MFMA GEMM core ----------------
// 256 threads = 4 waves. BM=128, BN=128, BK=32, K=256 fixed, A/B row stride 256 (K-major).
// A = [M][256] bf16 row-major; B = [N][256] bf16 row-major (i.e., weights as stored).
// Wave w covers rows (w&1)*64, cols (w>>1)*64: 4x4 grid of 16x16 MFMA tiles.
// LDS: As[128][32] at 0, Bs[128][32] at 4096 (ushort units). Staged via global_load_lds x16B.

__device__ __forceinline__ void gemm_core(const ushort* __restrict__ A,
                                          const ushort* __restrict__ B,
                                          ushort* lds, int bm, int bn,
                                          floatx4 acc[4][4]) {
    const int tid = threadIdx.x;
    const int w = tid >> 6, lane = tid & 63;
    const int q = lane >> 4, mr = lane & 15;
    const int wm = (w & 1) << 6, wn = (w >> 1) << 6;
    const int srow0 = (w << 5) + (lane >> 2);   // staging row, i=0 half
    const int scol  = (lane & 3) << 3;          // ushort offset within row (16B granules)
    for (int k0 = 0; k0 < 256; k0 += 32) {
        #pragma unroll
        for (int i = 0; i < 2; ++i) {
            int r = srow0 + (i << 4);
            gload_lds16(A + (size_t)(bm + r) * 256 + k0 + scol,
                        lds + ((w << 5) + (i << 4)) * 32);
            gload_lds16(B + (size_t)(bn + r) * 256 + k0 + scol,
                        lds + 4096 + ((w << 5) + (i << 4)) * 32);
        }
        __syncthreads();
        short8 af[4], bf[4];
        #pragma unroll
        for (int i = 0; i < 4; ++i)
            af[i] = *(const short8*)&lds[(wm + (i << 4) + mr) * 32 + (q << 3)];
        #pragma unroll
        for (int j = 0; j < 4; ++j)
            bf[j] = *(const short8*)&lds[4096 + (wn + (j << 4) + mr) * 32 + (q << 3)];
        #pragma unroll
        for (int i = 0; i < 4; ++i)
            #pragma unroll
            for (int j = 0; j < 4; ++j)
                acc[i][j] = __builtin_amdgcn_mfma_f32_16x16x32_bf16(af[i], bf[j], acc[i][j], 0, 0, 0);
        __syncthreads();
    }
}

// gemm1: h1 = relu(cat1 @ B1^T + b1), bf16 out, N=256 (grid.x=2), M=M_PAD
__global__ __launch_bounds__(256) void gemm1_k(const ushort* __restrict__ A,
                                               const ushort* __restrict__ B,
                                               const float* __restrict__ bias,
                                               ushort* __restrict__ C) {
    __shared__ __align__(16) ushort lds[8192];
    const int bm = blockIdx.y * 128, bn = blockIdx.x * 128;
    floatx4 acc[4][4];
    #pragma unroll
    for (int i = 0; i < 4; ++i)
        #pragma unroll
        for (int j = 0; j < 4; ++j)
            acc[i][j] = (floatx4){0.f, 0.f, 0.f, 0.f};
    gemm_core(A, B, lds, bm, bn, acc);
    const int tid = threadIdx.x, w = tid >> 6, lane = tid & 63;
    const int q = lane >> 4, mr = lane & 15;
    const int wm = (w & 1) << 6, wn = (w >> 1) << 6;
    #pragma unroll
    for (int i = 0; i < 4; ++i) {
        int row = bm + wm + (i << 4) + (q << 2);
        #pragma unroll
        for (int j = 0; j < 4; ++j) {
            int col = bn + wn + (j << 4) + mr;
            float b = bias[col];
            #pragma unroll
            for (int r = 0; r < 4; ++r) {
                float v = fmaxf(acc[i][j][r] + b, 0.f);
                C[(size_t)(row + r) * 256 + col] = f2bf(v);
            }
        }
    }
}

// gemm2: [t2|u2] = h1 @ B2^T, N=128 (bn=0), cols 0..63 -> t2 bf16, 64..127 -> u2 fp32
__global__ __launch_bounds__(256) void gemm2_k(const ushort* __restrict__ A,
                                               const ushort* __restrict__ B,
                                               ushort* __restrict__ t2,
                                               float* __restrict__ u2) {
    __shared__ __align__(16) ushort lds[8192];
    const int bm = blockIdx.x * 128;
    floatx4 acc[4][4];
    #pragma unroll
    for (int i = 0; i < 4; ++i)
        #pragma unroll
        for (int j = 0; j < 4; ++j)
            acc[i][j] = (floatx4){0.f, 0.f, 0.f, 0.f};
    gemm_core(A, B, lds, bm, 0, acc);
    const int tid = threadIdx.x, w = tid >> 6, lane = tid & 63;
    const int q = lane >> 4, mr = lane & 15;
    const int wm = (w & 1) << 6, wn = (w >> 1) << 6;
    #pragma unroll
    for (int i = 0; i < 4; ++i) {
        int row = bm + wm + (i << 4) + (q << 2);
        #pragma unroll
        for (int j = 0; j < 4; ++j) {
            int col = wn + (j << 4) + mr;
            #pragma unroll
            for (int r = 0; r < 4; ++r) {
                float v = acc[i][j][r];
                if (col < 64) t2[(size_t)(row + r) * 64 + col] = f2bf(v);
                else          u2[(size_t)(row + r) * 64 + (col - 64)] = v;
            }
        }
    }
}

// ---------------- launch ----------------

extern "C" void kernel_launch(void* const* d_in, const int* in_sizes, int n_in,
                              void* d_out, int out_size, void* d_ws, size_t ws_size,
                              hipStream_t stream) {
    const float* x   = (const float*)d_in[0];
    const int*   ei  = (const int*)d_in[1];
    const float* W1l = (const float*)d_in[2];
    const float* W1r = (const float*)d_in[3];
    const float* b1  = (const float*)d_in[4];
    const float* W2l = (const float*)d_in[5];
    const float* W2r = (const float*)d_in[6];
    const float* b2  = (const float*)d_in[7];
    float* out = (float*)d_out;

    char* base = (char*)d_ws;
    size_t off = 0;
    auto alloc = [&](size_t bytes) -> void* {
        void* p = base + off;
        off = (off + bytes + 255) & ~(size_t)255;
        return p;
    };
    int*    deg    = (int*)alloc(M_PAD * 4);
    int*    cursor = (int*)alloc(M_PAD * 4);
    int*    rs     = (int*)alloc(M_PAD * 4);
    int*    bsums  = (int*)alloc(64 * 4);
    float*  inv    = (float*)alloc(M_PAD * 4);
    int*    csr    = (int*)alloc((size_t)N_EDGES * 4);
    uint*   xb     = (uint*)alloc((size_t)N_NODES * 64 * 4);        // bf16 x, packed 2/uint
    uint*   cat1   = (uint*)alloc((size_t)M_PAD * 128 * 4);         // bf16 [M_PAD][256]
    ushort* h1     = (ushort*)alloc((size_t)M_PAD * 256 * 2);       // bf16
    ushort* t2     = (ushort*)alloc((size_t)M_PAD * 64 * 2);        // bf16
    float*  u2     = (float*)alloc((size_t)M_PAD * 64 * 4);         // fp32
    ushort* B1     = (ushort*)alloc(256 * 256 * 2);
    ushort* B2     = (ushort*)alloc(128 * 256 * 2);

    hipMemsetAsync(deg, 0, N_NODES * sizeof(int), stream);
    hipMemsetAsync(cursor, 0, N_NODES * sizeof(int), stream);

    convert_x_k<<<(N_NODES * 64 + 255) / 256, 256, 0, stream>>>((const float2*)x, xb);
    prep_w_k<<<384, 256, 0, stream>>>(W1l, W1r, W2l, W2r, B1, B2);

    deg_count_k<<<(N_EDGES + 255) / 256, 256, 0, stream>>>(ei, deg);
    scan_block_k<<<49, 1024, 0, stream>>>(deg, rs, bsums);
    scan_sums_k<<<1, 64, 0, stream>>>(bsums);
    scan_add_inv_k<<<49, 1024, 0, stream>>>(deg, rs, bsums, inv);
    fill_k<<<(N_EDGES + 255) / 256, 256, 0, stream>>>(ei, rs, cursor, csr);

    agg1_k<<<(N_NODES + 3) / 4, 256, 0, stream>>>(rs, deg, csr, xb, inv, cat1);

    {
        dim3 grid(2, M_PAD / 128);
        gemm1_k<<<grid, 256, 0, stream>>>((const ushort*)cat1, B1, b1, h1);
    }
    gemm2_k<<<M_PAD / 128, 256, 0, stream>>>(h1, B2, t2, u2);

    final_k<<<(N_NODES + 3) / 4, 256, 0, stream>>>(rs, deg, csr, t2, u2, b2, inv, out);
}

// Round 3
// 274.226 us; speedup vs baseline: 1.8443x; 1.1935x over previous
//
#include <hip/hip_runtime.h>
#include <hip/hip_bf16.h>

// GraphSAGE 2-layer forward, bf16-MFMA inner pipeline.
// R3: wide-gather restructure of agg1/final — 16B/lane loads, 4 (agg1) / 8 (final)
// edges in flight per wave-iteration, cross-group shfl_xor reduce per node.

#define N_NODES 50000
#define N_EDGES 800000
#define M_PAD   50048   // 391 * 128

typedef unsigned int uint;
typedef unsigned short ushort;
typedef __attribute__((ext_vector_type(8))) short short8;
typedef __attribute__((ext_vector_type(4))) float floatx4;

__device__ __forceinline__ ushort f2bf(float f) {
    union { float f; uint u; } c; c.f = f;
    uint u = c.u;
    return (ushort)((u + 0x7FFFu + ((u >> 16) & 1u)) >> 16);  // RNE
}
__device__ __forceinline__ uint pack2(float lo, float hi) {
    return (uint)f2bf(lo) | ((uint)f2bf(hi) << 16);
}
__device__ __forceinline__ float bflo(uint v) { return __uint_as_float(v << 16); }
__device__ __forceinline__ float bfhi(uint v) { return __uint_as_float(v & 0xffff0000u); }
__device__ __forceinline__ void gload_lds16(const ushort* g, ushort* l) {
    __builtin_amdgcn_global_load_lds(
        (const __attribute__((address_space(1))) void*)g,
        (__attribute__((address_space(3))) void*)l, 16, 0, 0);
}

// ---------------- dtype prep ----------------

__global__ void convert_x_k(const float2* __restrict__ x2, uint* __restrict__ xb) {
    int i = blockIdx.x * 256 + threadIdx.x;
    if (i >= N_NODES * 64) return;
    float2 v = x2[i];
    xb[i] = pack2(v.x, v.y);
}

__global__ void prep_w_k(const float* __restrict__ W1l, const float* __restrict__ W1r,
                         const float* __restrict__ W2l, const float* __restrict__ W2r,
                         ushort* __restrict__ B1, ushort* __restrict__ B2) {
    int t = blockIdx.x * 256 + threadIdx.x;
    if (t < 65536) {                       // B1[n][k], n<256, k<256
        int n = t >> 8, k = t & 255;
        float v = (k < 128) ? W1l[n * 128 + k] : W1r[n * 128 + (k - 128)];
        B1[t] = f2bf(v);
    } else if (t < 98304) {                // B2[n][k], n<128, k<256
        int t2 = t - 65536;
        int n = t2 >> 8, k = t2 & 255;
        float v = (n < 64) ? W2l[n * 256 + k] : W2r[(n - 64) * 256 + k];
        B2[t2] = f2bf(v);
    }
}

// ---------------- CSR build ----------------

__global__ void deg_count_k(const int* __restrict__ ei, int* __restrict__ deg) {
    int e = blockIdx.x * 256 + threadIdx.x;
    if (e < N_EDGES) atomicAdd(&deg[ei[N_EDGES + e]], 1);
}

__global__ __launch_bounds__(1024) void scan_block_k(const int* __restrict__ deg,
                                                     int* __restrict__ rs,
                                                     int* __restrict__ bsums) {
    __shared__ int wsum[16];
    const int tid = threadIdx.x, lane = tid & 63, wid = tid >> 6;
    int i = blockIdx.x * 1024 + tid;
    int v = (i < N_NODES) ? deg[i] : 0;
    int sc = v;
    #pragma unroll
    for (int off = 1; off < 64; off <<= 1) {
        int t = __shfl_up(sc, off);
        if (lane >= off) sc += t;
    }
    if (lane == 63) wsum[wid] = sc;
    __syncthreads();
    if (wid == 0) {
        int ws = (lane < 16) ? wsum[lane] : 0;
        #pragma unroll
        for (int off = 1; off < 16; off <<= 1) {
            int t = __shfl_up(ws, off);
            if (lane >= off) ws += t;
        }
        if (lane < 16) wsum[lane] = ws;
    }
    __syncthreads();
    int woff = wid ? wsum[wid - 1] : 0;
    if (i < N_NODES) rs[i] = woff + sc - v;          // block-local exclusive
    if (tid == 1023) bsums[blockIdx.x] = wsum[15];
}

__global__ void scan_sums_k(int* __restrict__ bsums) {   // 49 sums -> exclusive, 1 wave
    int lane = threadIdx.x;
    int v = (lane < 49) ? bsums[lane] : 0;
    int sc = v;
    #pragma unroll
    for (int off = 1; off < 64; off <<= 1) {
        int t = __shfl_up(sc, off);
        if (lane >= off) sc += t;
    }
    if (lane < 49) bsums[lane] = sc - v;
}

__global__ __launch_bounds__(1024) void scan_add_inv_k(const int* __restrict__ deg,
                                                       int* __restrict__ rs,
                                                       const int* __restrict__ bsums,
                                                       float* __restrict__ inv) {
    int i = blockIdx.x * 1024 + threadIdx.x;
    if (i < N_NODES) {
        rs[i] += bsums[blockIdx.x];
        inv[i] = 1.0f / fmaxf((float)deg[i], 1.0f);
    }
}

__global__ void fill_k(const int* __restrict__ ei, const int* __restrict__ rs,
                       int* __restrict__ cursor, int* __restrict__ csr) {
    int e = blockIdx.x * 256 + threadIdx.x;
    if (e >= N_EDGES) return;
    int d = ei[N_EDGES + e];
    int pos = atomicAdd(&cursor[d], 1);
    csr[rs[d] + pos] = ei[e];
}

// ---------------- aggregation (wide-gather) ----------------

// agg1: cat1[n] = [ mean xb[src] | xb[n] ] (bf16 rows of 256).
// Row = 64 uints = 16 lanes x uint4. Lane-group g=lane>>4 handles edge slot i*4+g:
// 4 rows in flight per wave-iteration. Partial sums reduced across groups via shfl_xor.
__global__ __launch_bounds__(256) void agg1_k(
        const int* __restrict__ rs, const int* __restrict__ deg,
        const int* __restrict__ csr, const uint* __restrict__ xb,
        const float* __restrict__ inv, uint* __restrict__ cat1) {
    const int wid = threadIdx.x >> 6, lane = threadIdx.x & 63;
    const int n = blockIdx.x * 4 + wid;
    if (n >= N_NODES) return;
    const int g = lane >> 4, sub = lane & 15;
    const int beg = rs[n], cnt = deg[n];
    float a0 = 0.f, a1 = 0.f, a2 = 0.f, a3 = 0.f, a4 = 0.f, a5 = 0.f, a6 = 0.f, a7 = 0.f;
    for (int i0 = 0; i0 < cnt; i0 += 64) {
        int rem = cnt - i0; if (rem > 64) rem = 64;
        int idxv = (lane < rem) ? csr[beg + i0 + lane] : 0;
        int nIter = (rem + 3) >> 2;
        #pragma unroll 4
        for (int i = 0; i < nIter; ++i) {
            int slot = (i << 2) + g;                 // < 64 always
            int src = __shfl(idxv, slot);
            uint4 v = *(const uint4*)(xb + (size_t)src * 64 + (sub << 2));
            if (slot < rem) {
                a0 += bflo(v.x); a1 += bfhi(v.x);
                a2 += bflo(v.y); a3 += bfhi(v.y);
                a4 += bflo(v.z); a5 += bfhi(v.z);
                a6 += bflo(v.w); a7 += bfhi(v.w);
            }
        }
    }
    // combine the 4 lane-groups (bits 4,5 of lane)
    a0 += __shfl_xor(a0, 16); a0 += __shfl_xor(a0, 32);
    a1 += __shfl_xor(a1, 16); a1 += __shfl_xor(a1, 32);
    a2 += __shfl_xor(a2, 16); a2 += __shfl_xor(a2, 32);
    a3 += __shfl_xor(a3, 16); a3 += __shfl_xor(a3, 32);
    a4 += __shfl_xor(a4, 16); a4 += __shfl_xor(a4, 32);
    a5 += __shfl_xor(a5, 16); a5 += __shfl_xor(a5, 32);
    a6 += __shfl_xor(a6, 16); a6 += __shfl_xor(a6, 32);
    a7 += __shfl_xor(a7, 16); a7 += __shfl_xor(a7, 32);
    if (g == 0) {
        float w = inv[n];
        uint4 o;
        o.x = pack2(a0 * w, a1 * w);
        o.y = pack2(a2 * w, a3 * w);
        o.z = pack2(a4 * w, a5 * w);
        o.w = pack2(a6 * w, a7 * w);
        *(uint4*)(cat1 + (size_t)n * 128 + (sub << 2)) = o;
    }
    cat1[(size_t)n * 128 + 64 + lane] = xb[(size_t)n * 64 + lane];  // root copy
}

// final: out[n] = u2[n] + b2 + invdeg * sum t2[src].
// t2 row = 32 uints (64 bf16) = 8 lanes x uint4: 8 edges in flight per iteration.
__global__ __launch_bounds__(256) void final_k(
        const int* __restrict__ rs, const int* __restrict__ deg,
        const int* __restrict__ csr, const uint* __restrict__ t2,
        const float* __restrict__ u2, const float* __restrict__ b2,
        const float* __restrict__ inv, float* __restrict__ out) {
    const int wid = threadIdx.x >> 6, lane = threadIdx.x & 63;
    const int n = blockIdx.x * 4 + wid;
    if (n >= N_NODES) return;
    const int g = lane >> 3, sub = lane & 7;
    const int beg = rs[n], cnt = deg[n];
    float a0 = 0.f, a1 = 0.f, a2 = 0.f, a3 = 0.f, a4 = 0.f, a5 = 0.f, a6 = 0.f, a7 = 0.f;
    for (int i0 = 0; i0 < cnt; i0 += 64) {
        int rem = cnt - i0; if (rem > 64) rem = 64;
        int idxv = (lane < rem) ? csr[beg + i0 + lane] : 0;
        int nIter = (rem + 7) >> 3;
        #pragma unroll 4
        for (int i = 0; i < nIter; ++i) {
            int slot = (i << 3) + g;                 // < 64 always
            int src = __shfl(idxv, slot);
            uint4 v = *(const uint4*)(t2 + (size_t)src * 32 + (sub << 2));
            if (slot < rem) {
                a0 += bflo(v.x); a1 += bfhi(v.x);
                a2 += bflo(v.y); a3 += bfhi(v.y);
                a4 += bflo(v.z); a5 += bfhi(v.z);
                a6 += bflo(v.w); a7 += bfhi(v.w);
            }
        }
    }
    // combine the 8 lane-groups (bits 3,4,5 of lane)
    a0 += __shfl_xor(a0, 8); a0 += __shfl_xor(a0, 16); a0 += __shfl_xor(a0, 32);
    a1 += __shfl_xor(a1, 8); a1 += __shfl_xor(a1, 16); a1 += __shfl_xor(a1, 32);
    a2 += __shfl_xor(a2, 8); a2 += __shfl_xor(a2, 16); a2 += __shfl_xor(a2, 32);
    a3 += __shfl_xor(a3, 8); a3 += __shfl_xor(a3, 16); a3 += __shfl_xor(a3, 32);
    a4 += __shfl_xor(a4, 8); a4 += __shfl_xor(a4, 16); a4 += __shfl_xor(a4, 32);
    a5 += __shfl_xor(a5, 8); a5 += __shfl_xor(a5, 16); a5 += __shfl_xor(a5, 32);
    a6 += __shfl_xor(a6, 8); a6 += __shfl_xor(a6, 16); a6 += __shfl_xor(a6, 32);
    a7 += __shfl_xor(a7, 8); a7 += __shfl_xor(a7, 16); a7 += __shfl_xor(a7, 32);
    if (g == 0) {
        float w = inv[n];
        const float* ur = u2 + (size_t)n * 64 + (sub << 3);
        float4 u0 = *(const float4*)ur;
        float4 u1 = *(const float4*)(ur + 4);
        const float* br = b2 + (sub << 3);
        float4 o0, o1;
        o0.x = u0.x + br[0] + a0 * w; o0.y = u0.y + br[1] + a1 * w;
        o0.z = u0.z + br[2] + a2 * w; o0.w = u0.w + br[3] + a3 * w;
        o1.x = u1.x + br[4] + a4 * w; o1.y = u1.y + br[5] + a5 * w;
        o1.z = u1.z + br[6] + a6 * w; o1.w = u1.w + br[7] + a7 * w;
        float* orow = out + (size_t)n * 64 + (sub << 3);
        *(float4*)orow = o0;
        *(float4*)(orow + 4) = o1;
    }
}

// ---------------- bf16 MFMA GEMM core ----------------
// 256 threads = 4 waves. BM=128, BN=128, BK=32, K=256 fixed, A/B row stride 256 (K-major).

__device__ __forceinline__ void gemm_core(const ushort* __restrict__ A,
                                          const ushort* __restrict__ B,
                                          ushort* lds, int bm, int bn,
                                          floatx4 acc[4][4]) {
    const int tid = threadIdx.x;
    const int w = tid >> 6, lane = tid & 63;
    const int q = lane >> 4, mr = lane & 15;
    const int wm = (w & 1) << 6, wn = (w >> 1) << 6;
    const int srow0 = (w << 5) + (lane >> 2);   // staging row, i=0 half
    const int scol  = (lane & 3) << 3;          // ushort offset within row (16B granules)
    for (int k0 = 0; k0 < 256; k0 += 32) {
        #pragma unroll
        for (int i = 0; i < 2; ++i) {
            int r = srow0 + (i << 4);
            gload_lds16(A + (size_t)(bm + r) * 256 + k0 + scol,
                        lds + ((w << 5) + (i << 4)) * 32);
            gload_lds16(B + (size_t)(bn + r) * 256 + k0 + scol,
                        lds + 4096 + ((w << 5) + (i << 4)) * 32);
        }
        __syncthreads();
        short8 af[4], bf[4];
        #pragma unroll
        for (int i = 0; i < 4; ++i)
            af[i] = *(const short8*)&lds[(wm + (i << 4) + mr) * 32 + (q << 3)];
        #pragma unroll
        for (int j = 0; j < 4; ++j)
            bf[j] = *(const short8*)&lds[4096 + (wn + (j << 4) + mr) * 32 + (q << 3)];
        #pragma unroll
        for (int i = 0; i < 4; ++i)
            #pragma unroll
            for (int j = 0; j < 4; ++j)
                acc[i][j] = __builtin_amdgcn_mfma_f32_16x16x32_bf16(af[i], bf[j], acc[i][j], 0, 0, 0);
        __syncthreads();
    }
}

// gemm1: h1 = relu(cat1 @ B1^T + b1), bf16 out, N=256 (grid.x=2), M=M_PAD
__global__ __launch_bounds__(256) void gemm1_k(const ushort* __restrict__ A,
                                               const ushort* __restrict__ B,
                                               const float* __restrict__ bias,
                                               ushort* __restrict__ C) {
    __shared__ __align__(16) ushort lds[8192];
    const int bm = blockIdx.y * 128, bn = blockIdx.x * 128;
    floatx4 acc[4][4];
    #pragma unroll
    for (int i = 0; i < 4; ++i)
        #pragma unroll
        for (int j = 0; j < 4; ++j)
            acc[i][j] = (floatx4){0.f, 0.f, 0.f, 0.f};
    gemm_core(A, B, lds, bm, bn, acc);
    const int tid = threadIdx.x, w = tid >> 6, lane = tid & 63;
    const int q = lane >> 4, mr = lane & 15;
    const int wm = (w & 1) << 6, wn = (w >> 1) << 6;
    #pragma unroll
    for (int i = 0; i < 4; ++i) {
        int row = bm + wm + (i << 4) + (q << 2);
        #pragma unroll
        for (int j = 0; j < 4; ++j) {
            int col = bn + wn + (j << 4) + mr;
            float b = bias[col];
            #pragma unroll
            for (int r = 0; r < 4; ++r) {
                float v = fmaxf(acc[i][j][r] + b, 0.f);
                C[(size_t)(row + r) * 256 + col] = f2bf(v);
            }
        }
    }
}

// gemm2: [t2|u2] = h1 @ B2^T, N=128 (bn=0), cols 0..63 -> t2 bf16, 64..127 -> u2 fp32
__global__ __launch_bounds__(256) void gemm2_k(const ushort* __restrict__ A,
                                               const ushort* __restrict__ B,
                                               ushort* __restrict__ t2,
                                               float* __restrict__ u2) {
    __shared__ __align__(16) ushort lds[8192];
    const int bm = blockIdx.x * 128;
    floatx4 acc[4][4];
    #pragma unroll
    for (int i = 0; i < 4; ++i)
        #pragma unroll
        for (int j = 0; j < 4; ++j)
            acc[i][j] = (floatx4){0.f, 0.f, 0.f, 0.f};
    gemm_core(A, B, lds, bm, 0, acc);
    const int tid = threadIdx.x, w = tid >> 6, lane = tid & 63;
    const int q = lane >> 4, mr = lane & 15;
    const int wm = (w & 1) << 6, wn = (w >> 1) << 6;
    #pragma unroll
    for (int i = 0; i < 4; ++i) {
        int row = bm + wm + (i << 4) + (q << 2);
        #pragma unroll
        for (int j = 0; j < 4; ++j) {
            int col = wn + (j << 4) + mr;
            #pragma unroll
            for (int r = 0; r < 4; ++r) {
                float v = acc[i][j][r];
                if (col < 64) t2[(size_t)(row + r) * 64 + col] = f2bf(v);
                else          u2[(size_t)(row + r) * 64 + (col - 64)] = v;
            }
        }
    }
}

// ---------------- launch ----------------

extern "C" void kernel_launch(void* const* d_in, const int* in_sizes, int n_in,
                              void* d_out, int out_size, void* d_ws, size_t ws_size,
                              hipStream_t stream) {
    const float* x   = (const float*)d_in[0];
    const int*   ei  = (const int*)d_in[1];
    const float* W1l = (const float*)d_in[2];
    const float* W1r = (const float*)d_in[3];
    const float* b1  = (const float*)d_in[4];
    const float* W2l = (const float*)d_in[5];
    const float* W2r = (const float*)d_in[6];
    const float* b2  = (const float*)d_in[7];
    float* out = (float*)d_out;

    char* base = (char*)d_ws;
    size_t off = 0;
    auto alloc = [&](size_t bytes) -> void* {
        void* p = base + off;
        off = (off + bytes + 255) & ~(size_t)255;
        return p;
    };
    int*    deg    = (int*)alloc(M_PAD * 4);
    int*    cursor = (int*)alloc(M_PAD * 4);
    int*    rs     = (int*)alloc(M_PAD * 4);
    int*    bsums  = (int*)alloc(64 * 4);
    float*  inv    = (float*)alloc(M_PAD * 4);
    int*    csr    = (int*)alloc((size_t)N_EDGES * 4);
    uint*   xb     = (uint*)alloc((size_t)N_NODES * 64 * 4);        // bf16 x, packed 2/uint
    uint*   cat1   = (uint*)alloc((size_t)M_PAD * 128 * 4);         // bf16 [M_PAD][256]
    ushort* h1     = (ushort*)alloc((size_t)M_PAD * 256 * 2);       // bf16
    uint*   t2     = (uint*)alloc((size_t)M_PAD * 32 * 4);          // bf16 [M_PAD][64]
    float*  u2     = (float*)alloc((size_t)M_PAD * 64 * 4);         // fp32
    ushort* B1     = (ushort*)alloc(256 * 256 * 2);
    ushort* B2     = (ushort*)alloc(128 * 256 * 2);

    hipMemsetAsync(deg, 0, N_NODES * sizeof(int), stream);
    hipMemsetAsync(cursor, 0, N_NODES * sizeof(int), stream);

    convert_x_k<<<(N_NODES * 64 + 255) / 256, 256, 0, stream>>>((const float2*)x, xb);
    prep_w_k<<<384, 256, 0, stream>>>(W1l, W1r, W2l, W2r, B1, B2);

    deg_count_k<<<(N_EDGES + 255) / 256, 256, 0, stream>>>(ei, deg);
    scan_block_k<<<49, 1024, 0, stream>>>(deg, rs, bsums);
    scan_sums_k<<<1, 64, 0, stream>>>(bsums);
    scan_add_inv_k<<<49, 1024, 0, stream>>>(deg, rs, bsums, inv);
    fill_k<<<(N_EDGES + 255) / 256, 256, 0, stream>>>(ei, rs, cursor, csr);

    agg1_k<<<(N_NODES + 3) / 4, 256, 0, stream>>>(rs, deg, csr, xb, inv, cat1);

    {
        dim3 grid(2, M_PAD / 128);
        gemm1_k<<<grid, 256, 0, stream>>>((const ushort*)cat1, B1, b1, h1);
    }
    gemm2_k<<<M_PAD / 128, 256, 0, stream>>>(h1, B2, (ushort*)t2, u2);

    final_k<<<(N_NODES + 3) / 4, 256, 0, stream>>>(rs, deg, csr, t2, u2, b2, inv, out);
}

// Round 4
// 214.900 us; speedup vs baseline: 2.3535x; 1.2761x over previous
//
#include <hip/hip_runtime.h>
#include <hip/hip_bf16.h>

// GraphSAGE 2-layer forward, bf16-MFMA inner pipeline.
// R4: CSR build via 2-phase bucket partition (dst>>7 -> 391 buckets of 128 nodes).
//   partition_k: LDS-histogram + per-(block,bucket) reservation -> part[] regions
//   bucket_scan_k: 391-value scan -> csr bases
//   build_k: per-bucket LDS degree/scan/cursor -> csr + rs/deg/inv (no global atomics,
//            csr writes dense in an 8KB window -> no write amplification)

#define N_NODES 50000
#define N_EDGES 800000
#define M_PAD   50048   // 391 * 128

#define BUCK_SHIFT 7
#define K_BUCK 391            // ceil(50000/128)
#define BUCK_CAP 4096         // mean 2046, sigma ~45 -> never exceeded (guarded anyway)
#define P1_EPB 16             // edges per thread in partition_k (4096/block)

typedef unsigned int uint;
typedef unsigned short ushort;
typedef __attribute__((ext_vector_type(8))) short short8;
typedef __attribute__((ext_vector_type(4))) float floatx4;

__device__ __forceinline__ ushort f2bf(float f) {
    union { float f; uint u; } c; c.f = f;
    uint u = c.u;
    return (ushort)((u + 0x7FFFu + ((u >> 16) & 1u)) >> 16);  // RNE
}
__device__ __forceinline__ uint pack2(float lo, float hi) {
    return (uint)f2bf(lo) | ((uint)f2bf(hi) << 16);
}
__device__ __forceinline__ float bflo(uint v) { return __uint_as_float(v << 16); }
__device__ __forceinline__ float bfhi(uint v) { return __uint_as_float(v & 0xffff0000u); }
__device__ __forceinline__ void gload_lds16(const ushort* g, ushort* l) {
    __builtin_amdgcn_global_load_lds(
        (const __attribute__((address_space(1))) void*)g,
        (__attribute__((address_space(3))) void*)l, 16, 0, 0);
}

// ---------------- fused dtype prep ----------------

__global__ void prep_k(const float2* __restrict__ x2, uint* __restrict__ xb,
                       const float* __restrict__ W1l, const float* __restrict__ W1r,
                       const float* __restrict__ W2l, const float* __restrict__ W2r,
                       ushort* __restrict__ B1, ushort* __restrict__ B2) {
    int i = blockIdx.x * 256 + threadIdx.x;
    if (i < N_NODES * 64) {
        float2 v = x2[i];
        xb[i] = pack2(v.x, v.y);
        return;
    }
    int t = i - N_NODES * 64;
    if (t < 65536) {                       // B1[n][k], n<256, k<256
        int n = t >> 8, k = t & 255;
        float v = (k < 128) ? W1l[n * 128 + k] : W1r[n * 128 + (k - 128)];
        B1[t] = f2bf(v);
    } else if (t < 98304) {                // B2[n][k], n<128, k<256
        int t2 = t - 65536;
        int n = t2 >> 8, k = t2 & 255;
        float v = (n < 64) ? W2l[n * 256 + k] : W2r[(n - 64) * 256 + k];
        B2[t2] = f2bf(v);
    }
}

// ---------------- CSR build: 2-phase bucket partition ----------------

__global__ __launch_bounds__(256) void partition_k(const int* __restrict__ ei,
                                                   int* __restrict__ bucket_cnt,
                                                   int2* __restrict__ part) {
    __shared__ int hist[K_BUCK];
    __shared__ int goff[K_BUCK];
    const int tid = threadIdx.x;
    for (int i = tid; i < K_BUCK; i += 256) hist[i] = 0;
    __syncthreads();
    const int e0 = blockIdx.x * (256 * P1_EPB);
    int srcv[P1_EPB], dstv[P1_EPB];
    #pragma unroll
    for (int i = 0; i < P1_EPB; ++i) {
        int e = e0 + tid + (i << 8);
        bool ok = e < N_EDGES;
        srcv[i] = ok ? ei[e] : 0;
        dstv[i] = ok ? ei[N_EDGES + e] : -1;
        if (ok) atomicAdd(&hist[dstv[i] >> BUCK_SHIFT], 1);
    }
    __syncthreads();
    for (int b = tid; b < K_BUCK; b += 256) {
        int c = hist[b];
        goff[b] = c ? atomicAdd(&bucket_cnt[b], c) : 0;
        hist[b] = 0;                        // reuse as block-local cursor
    }
    __syncthreads();
    #pragma unroll
    for (int i = 0; i < P1_EPB; ++i) {
        if (dstv[i] >= 0) {
            int b = dstv[i] >> BUCK_SHIFT;
            int pos = goff[b] + atomicAdd(&hist[b], 1);
            if (pos < BUCK_CAP)             // memory-safety guard (statistically impossible)
                part[(size_t)b * BUCK_CAP + pos] = make_int2(srcv[i], dstv[i]);
        }
    }
}

__global__ void bucket_scan_k(const int* __restrict__ cnt, int* __restrict__ bbase) {
    const int lane = threadIdx.x;           // single wave
    int carry = 0;
    for (int c = 0; c < K_BUCK; c += 64) {
        int i = c + lane;
        int v = (i < K_BUCK) ? cnt[i] : 0;
        int sc = v;
        #pragma unroll
        for (int off = 1; off < 64; off <<= 1) {
            int t = __shfl_up(sc, off);
            if (lane >= off) sc += t;
        }
        if (i < K_BUCK) bbase[i] = carry + sc - v;
        carry += __shfl(sc, 63);
    }
}

__global__ __launch_bounds__(256) void build_k(const int2* __restrict__ part,
                                               const int* __restrict__ bucket_cnt,
                                               const int* __restrict__ bbase,
                                               int* __restrict__ rs, int* __restrict__ deg_g,
                                               float* __restrict__ inv, int* __restrict__ csr) {
    __shared__ int degl[128], rsl[128], cur[128];
    const int b = blockIdx.x;
    const int tid = threadIdx.x;
    int Eb = bucket_cnt[b]; if (Eb > BUCK_CAP) Eb = BUCK_CAP;
    const int base = bbase[b];
    const int2* pe = part + (size_t)b * BUCK_CAP;
    if (tid < 128) degl[tid] = 0;
    __syncthreads();
    for (int i = tid; i < Eb; i += 256)
        atomicAdd(&degl[pe[i].y & 127], 1);
    __syncthreads();
    if (tid < 64) {                          // wave 0 scans 128 counters
        int carry = 0;
        for (int c = 0; c < 128; c += 64) {
            int v = degl[c + tid];
            int sc = v;
            #pragma unroll
            for (int off = 1; off < 64; off <<= 1) {
                int t = __shfl_up(sc, off);
                if (tid >= off) sc += t;
            }
            rsl[c + tid] = carry + sc - v;
            carry += __shfl(sc, 63);
        }
    }
    __syncthreads();
    if (tid < 128) {
        int n = (b << BUCK_SHIFT) + tid;
        if (n < N_NODES) {
            int d = degl[tid];
            rs[n] = base + rsl[tid];
            deg_g[n] = d;
            inv[n] = 1.0f / fmaxf((float)d, 1.0f);
        }
        cur[tid] = 0;
    }
    __syncthreads();
    for (int i = tid; i < Eb; i += 256) {
        int2 e = pe[i];
        int ld = e.y & 127;
        int pos = atomicAdd(&cur[ld], 1);
        csr[base + rsl[ld] + pos] = e.x;    // dense 8KB window, single block
    }
}

// ---------------- aggregation (wide-gather) ----------------

__global__ __launch_bounds__(256) void agg1_k(
        const int* __restrict__ rs, const int* __restrict__ deg,
        const int* __restrict__ csr, const uint* __restrict__ xb,
        const float* __restrict__ inv, uint* __restrict__ cat1) {
    const int wid = threadIdx.x >> 6, lane = threadIdx.x & 63;
    const int n = blockIdx.x * 4 + wid;
    if (n >= N_NODES) return;
    const int g = lane >> 4, sub = lane & 15;
    const int beg = rs[n], cnt = deg[n];
    float a0 = 0.f, a1 = 0.f, a2 = 0.f, a3 = 0.f, a4 = 0.f, a5 = 0.f, a6 = 0.f, a7 = 0.f;
    for (int i0 = 0; i0 < cnt; i0 += 64) {
        int rem = cnt - i0; if (rem > 64) rem = 64;
        int idxv = (lane < rem) ? csr[beg + i0 + lane] : 0;
        int nIter = (rem + 3) >> 2;
        #pragma unroll 4
        for (int i = 0; i < nIter; ++i) {
            int slot = (i << 2) + g;
            int src = __shfl(idxv, slot);
            uint4 v = *(const uint4*)(xb + (size_t)src * 64 + (sub << 2));
            if (slot < rem) {
                a0 += bflo(v.x); a1 += bfhi(v.x);
                a2 += bflo(v.y); a3 += bfhi(v.y);
                a4 += bflo(v.z); a5 += bfhi(v.z);
                a6 += bflo(v.w); a7 += bfhi(v.w);
            }
        }
    }
    a0 += __shfl_xor(a0, 16); a0 += __shfl_xor(a0, 32);
    a1 += __shfl_xor(a1, 16); a1 += __shfl_xor(a1, 32);
    a2 += __shfl_xor(a2, 16); a2 += __shfl_xor(a2, 32);
    a3 += __shfl_xor(a3, 16); a3 += __shfl_xor(a3, 32);
    a4 += __shfl_xor(a4, 16); a4 += __shfl_xor(a4, 32);
    a5 += __shfl_xor(a5, 16); a5 += __shfl_xor(a5, 32);
    a6 += __shfl_xor(a6, 16); a6 += __shfl_xor(a6, 32);
    a7 += __shfl_xor(a7, 16); a7 += __shfl_xor(a7, 32);
    if (g == 0) {
        float w = inv[n];
        uint4 o;
        o.x = pack2(a0 * w, a1 * w);
        o.y = pack2(a2 * w, a3 * w);
        o.z = pack2(a4 * w, a5 * w);
        o.w = pack2(a6 * w, a7 * w);
        *(uint4*)(cat1 + (size_t)n * 128 + (sub << 2)) = o;
    }
    cat1[(size_t)n * 128 + 64 + lane] = xb[(size_t)n * 64 + lane];  // root copy
}

__global__ __launch_bounds__(256) void final_k(
        const int* __restrict__ rs, const int* __restrict__ deg,
        const int* __restrict__ csr, const uint* __restrict__ t2,
        const float* __restrict__ u2, const float* __restrict__ b2,
        const float* __restrict__ inv, float* __restrict__ out) {
    const int wid = threadIdx.x >> 6, lane = threadIdx.x & 63;
    const int n = blockIdx.x * 4 + wid;
    if (n >= N_NODES) return;
    const int g = lane >> 3, sub = lane & 7;
    const int beg = rs[n], cnt = deg[n];
    float a0 = 0.f, a1 = 0.f, a2 = 0.f, a3 = 0.f, a4 = 0.f, a5 = 0.f, a6 = 0.f, a7 = 0.f;
    for (int i0 = 0; i0 < cnt; i0 += 64) {
        int rem = cnt - i0; if (rem > 64) rem = 64;
        int idxv = (lane < rem) ? csr[beg + i0 + lane] : 0;
        int nIter = (rem + 7) >> 3;
        #pragma unroll 4
        for (int i = 0; i < nIter; ++i) {
            int slot = (i << 3) + g;
            int src = __shfl(idxv, slot);
            uint4 v = *(const uint4*)(t2 + (size_t)src * 32 + (sub << 2));
            if (slot < rem) {
                a0 += bflo(v.x); a1 += bfhi(v.x);
                a2 += bflo(v.y); a3 += bfhi(v.y);
                a4 += bflo(v.z); a5 += bfhi(v.z);
                a6 += bflo(v.w); a7 += bfhi(v.w);
            }
        }
    }
    a0 += __shfl_xor(a0, 8); a0 += __shfl_xor(a0, 16); a0 += __shfl_xor(a0, 32);
    a1 += __shfl_xor(a1, 8); a1 += __shfl_xor(a1, 16); a1 += __shfl_xor(a1, 32);
    a2 += __shfl_xor(a2, 8); a2 += __shfl_xor(a2, 16); a2 += __shfl_xor(a2, 32);
    a3 += __shfl_xor(a3, 8); a3 += __shfl_xor(a3, 16); a3 += __shfl_xor(a3, 32);
    a4 += __shfl_xor(a4, 8); a4 += __shfl_xor(a4, 16); a4 += __shfl_xor(a4, 32);
    a5 += __shfl_xor(a5, 8); a5 += __shfl_xor(a5, 16); a5 += __shfl_xor(a5, 32);
    a6 += __shfl_xor(a6, 8); a6 += __shfl_xor(a6, 16); a6 += __shfl_xor(a6, 32);
    a7 += __shfl_xor(a7, 8); a7 += __shfl_xor(a7, 16); a7 += __shfl_xor(a7, 32);
    if (g == 0) {
        float w = inv[n];
        const float* ur = u2 + (size_t)n * 64 + (sub << 3);
        float4 u0 = *(const float4*)ur;
        float4 u1 = *(const float4*)(ur + 4);
        const float* br = b2 + (sub << 3);
        float4 o0, o1;
        o0.x = u0.x + br[0] + a0 * w; o0.y = u0.y + br[1] + a1 * w;
        o0.z = u0.z + br[2] + a2 * w; o0.w = u0.w + br[3] + a3 * w;
        o1.x = u1.x + br[4] + a4 * w; o1.y = u1.y + br[5] + a5 * w;
        o1.z = u1.z + br[6] + a6 * w; o1.w = u1.w + br[7] + a7 * w;
        float* orow = out + (size_t)n * 64 + (sub << 3);
        *(float4*)orow = o0;
        *(float4*)(orow + 4) = o1;
    }
}

// ---------------- bf16 MFMA GEMM core ----------------

__device__ __forceinline__ void gemm_core(const ushort* __restrict__ A,
                                          const ushort* __restrict__ B,
                                          ushort* lds, int bm, int bn,
                                          floatx4 acc[4][4]) {
    const int tid = threadIdx.x;
    const int w = tid >> 6, lane = tid & 63;
    const int q = lane >> 4, mr = lane & 15;
    const int wm = (w & 1) << 6, wn = (w >> 1) << 6;
    const int srow0 = (w << 5) + (lane >> 2);
    const int scol  = (lane & 3) << 3;
    for (int k0 = 0; k0 < 256; k0 += 32) {
        #pragma unroll
        for (int i = 0; i < 2; ++i) {
            int r = srow0 + (i << 4);
            gload_lds16(A + (size_t)(bm + r) * 256 + k0 + scol,
                        lds + ((w << 5) + (i << 4)) * 32);
            gload_lds16(B + (size_t)(bn + r) * 256 + k0 + scol,
                        lds + 4096 + ((w << 5) + (i << 4)) * 32);
        }
        __syncthreads();
        short8 af[4], bf[4];
        #pragma unroll
        for (int i = 0; i < 4; ++i)
            af[i] = *(const short8*)&lds[(wm + (i << 4) + mr) * 32 + (q << 3)];
        #pragma unroll
        for (int j = 0; j < 4; ++j)
            bf[j] = *(const short8*)&lds[4096 + (wn + (j << 4) + mr) * 32 + (q << 3)];
        #pragma unroll
        for (int i = 0; i < 4; ++i)
            #pragma unroll
            for (int j = 0; j < 4; ++j)
                acc[i][j] = __builtin_amdgcn_mfma_f32_16x16x32_bf16(af[i], bf[j], acc[i][j], 0, 0, 0);
        __syncthreads();
    }
}

__global__ __launch_bounds__(256) void gemm1_k(const ushort* __restrict__ A,
                                               const ushort* __restrict__ B,
                                               const float* __restrict__ bias,
                                               ushort* __restrict__ C) {
    __shared__ __align__(16) ushort lds[8192];
    const int bm = blockIdx.y * 128, bn = blockIdx.x * 128;
    floatx4 acc[4][4];
    #pragma unroll
    for (int i = 0; i < 4; ++i)
        #pragma unroll
        for (int j = 0; j < 4; ++j)
            acc[i][j] = (floatx4){0.f, 0.f, 0.f, 0.f};
    gemm_core(A, B, lds, bm, bn, acc);
    const int tid = threadIdx.x, w = tid >> 6, lane = tid & 63;
    const int q = lane >> 4, mr = lane & 15;
    const int wm = (w & 1) << 6, wn = (w >> 1) << 6;
    #pragma unroll
    for (int i = 0; i < 4; ++i) {
        int row = bm + wm + (i << 4) + (q << 2);
        #pragma unroll
        for (int j = 0; j < 4; ++j) {
            int col = bn + wn + (j << 4) + mr;
            float b = bias[col];
            #pragma unroll
            for (int r = 0; r < 4; ++r) {
                float v = fmaxf(acc[i][j][r] + b, 0.f);
                C[(size_t)(row + r) * 256 + col] = f2bf(v);
            }
        }
    }
}

__global__ __launch_bounds__(256) void gemm2_k(const ushort* __restrict__ A,
                                               const ushort* __restrict__ B,
                                               ushort* __restrict__ t2,
                                               float* __restrict__ u2) {
    __shared__ __align__(16) ushort lds[8192];
    const int bm = blockIdx.x * 128;
    floatx4 acc[4][4];
    #pragma unroll
    for (int i = 0; i < 4; ++i)
        #pragma unroll
        for (int j = 0; j < 4; ++j)
            acc[i][j] = (floatx4){0.f, 0.f, 0.f, 0.f};
    gemm_core(A, B, lds, bm, 0, acc);
    const int tid = threadIdx.x, w = tid >> 6, lane = tid & 63;
    const int q = lane >> 4, mr = lane & 15;
    const int wm = (w & 1) << 6, wn = (w >> 1) << 6;
    #pragma unroll
    for (int i = 0; i < 4; ++i) {
        int row = bm + wm + (i << 4) + (q << 2);
        #pragma unroll
        for (int j = 0; j < 4; ++j) {
            int col = wn + (j << 4) + mr;
            #pragma unroll
            for (int r = 0; r < 4; ++r) {
                float v = acc[i][j][r];
                if (col < 64) t2[(size_t)(row + r) * 64 + col] = f2bf(v);
                else          u2[(size_t)(row + r) * 64 + (col - 64)] = v;
            }
        }
    }
}

// ---------------- launch ----------------

extern "C" void kernel_launch(void* const* d_in, const int* in_sizes, int n_in,
                              void* d_out, int out_size, void* d_ws, size_t ws_size,
                              hipStream_t stream) {
    const float* x   = (const float*)d_in[0];
    const int*   ei  = (const int*)d_in[1];
    const float* W1l = (const float*)d_in[2];
    const float* W1r = (const float*)d_in[3];
    const float* b1  = (const float*)d_in[4];
    const float* W2l = (const float*)d_in[5];
    const float* W2r = (const float*)d_in[6];
    const float* b2  = (const float*)d_in[7];
    float* out = (float*)d_out;

    char* base = (char*)d_ws;
    size_t off = 0;
    auto alloc = [&](size_t bytes) -> void* {
        void* p = base + off;
        off = (off + bytes + 255) & ~(size_t)255;
        return p;
    };
    int*    deg        = (int*)alloc(M_PAD * 4);
    int*    rs         = (int*)alloc(M_PAD * 4);
    float*  inv        = (float*)alloc(M_PAD * 4);
    int*    bucket_cnt = (int*)alloc(K_BUCK * 4);
    int*    bbase      = (int*)alloc(K_BUCK * 4);
    int*    csr        = (int*)alloc((size_t)N_EDGES * 4);
    int2*   part       = (int2*)alloc((size_t)K_BUCK * BUCK_CAP * 8);
    uint*   xb         = (uint*)alloc((size_t)N_NODES * 64 * 4);
    uint*   cat1       = (uint*)alloc((size_t)M_PAD * 128 * 4);
    ushort* h1         = (ushort*)alloc((size_t)M_PAD * 256 * 2);
    uint*   t2         = (uint*)alloc((size_t)M_PAD * 32 * 4);
    float*  u2         = (float*)alloc((size_t)M_PAD * 64 * 4);
    ushort* B1         = (ushort*)alloc(256 * 256 * 2);
    ushort* B2         = (ushort*)alloc(128 * 256 * 2);

    hipMemsetAsync(bucket_cnt, 0, K_BUCK * sizeof(int), stream);

    prep_k<<<(N_NODES * 64 + 98304 + 255) / 256, 256, 0, stream>>>(
        (const float2*)x, xb, W1l, W1r, W2l, W2r, B1, B2);

    partition_k<<<(N_EDGES + 256 * P1_EPB - 1) / (256 * P1_EPB), 256, 0, stream>>>(
        ei, bucket_cnt, part);
    bucket_scan_k<<<1, 64, 0, stream>>>(bucket_cnt, bbase);
    build_k<<<K_BUCK, 256, 0, stream>>>(part, bucket_cnt, bbase, rs, deg, inv, csr);

    agg1_k<<<(N_NODES + 3) / 4, 256, 0, stream>>>(rs, deg, csr, xb, inv, cat1);

    {
        dim3 grid(2, M_PAD / 128);
        gemm1_k<<<grid, 256, 0, stream>>>((const ushort*)cat1, B1, b1, h1);
    }
    gemm2_k<<<M_PAD / 128, 256, 0, stream>>>(h1, B2, (ushort*)t2, u2);

    final_k<<<(N_NODES + 3) / 4, 256, 0, stream>>>(rs, deg, csr, t2, u2, b2, inv, out);
}

// Round 5
// 198.370 us; speedup vs baseline: 2.5496x; 1.0833x over previous
//
#include <hip/hip_runtime.h>
#include <hip/hip_bf16.h>

// GraphSAGE 2-layer forward, bf16-MFMA inner pipeline.
// R5: fused gemm12 (h1 never hits HBM; computed per-128-row-tile in LDS halves),
//     bucket_scan folded into build_k, memset folded into prep_k. 6 dispatches:
//     prep -> partition -> build -> agg1 -> gemm12 -> final.

#define N_NODES 50000
#define N_EDGES 800000
#define M_PAD   50048   // 391 * 128

#define BUCK_SHIFT 7
#define K_BUCK 391            // ceil(50000/128)
#define BUCK_CAP 4096         // mean 2046, sigma ~45 -> never exceeded (guarded anyway)
#define P1_EPB 16             // edges per thread in partition_k (4096/block)

typedef unsigned int uint;
typedef unsigned short ushort;
typedef __attribute__((ext_vector_type(8))) short short8;
typedef __attribute__((ext_vector_type(4))) float floatx4;

__device__ __forceinline__ ushort f2bf(float f) {
    union { float f; uint u; } c; c.f = f;
    uint u = c.u;
    return (ushort)((u + 0x7FFFu + ((u >> 16) & 1u)) >> 16);  // RNE
}
__device__ __forceinline__ uint pack2(float lo, float hi) {
    return (uint)f2bf(lo) | ((uint)f2bf(hi) << 16);
}
__device__ __forceinline__ float bflo(uint v) { return __uint_as_float(v << 16); }
__device__ __forceinline__ float bfhi(uint v) { return __uint_as_float(v & 0xffff0000u); }
__device__ __forceinline__ void gload_lds16(const ushort* g, ushort* l) {
    __builtin_amdgcn_global_load_lds(
        (const __attribute__((address_space(1))) void*)g,
        (__attribute__((address_space(3))) void*)l, 16, 0, 0);
}

// ---------------- fused dtype prep (+ bucket_cnt zero) ----------------

__global__ void prep_k(const float2* __restrict__ x2, uint* __restrict__ xb,
                       const float* __restrict__ W1l, const float* __restrict__ W1r,
                       const float* __restrict__ W2l, const float* __restrict__ W2r,
                       ushort* __restrict__ B1, ushort* __restrict__ B2,
                       int* __restrict__ bucket_cnt) {
    int i = blockIdx.x * 256 + threadIdx.x;
    if (i < N_NODES * 64) {
        float2 v = x2[i];
        xb[i] = pack2(v.x, v.y);
        return;
    }
    int t = i - N_NODES * 64;
    if (t < 65536) {                       // B1[n][k], n<256, k<256
        int n = t >> 8, k = t & 255;
        float v = (k < 128) ? W1l[n * 128 + k] : W1r[n * 128 + (k - 128)];
        B1[t] = f2bf(v);
    } else if (t < 98304) {                // B2[n][k], n<128, k<256
        int t2 = t - 65536;
        int n = t2 >> 8, k = t2 & 255;
        float v = (n < 64) ? W2l[n * 256 + k] : W2r[(n - 64) * 256 + k];
        B2[t2] = f2bf(v);
    } else if (t < 98304 + K_BUCK) {
        bucket_cnt[t - 98304] = 0;
    }
}

// ---------------- CSR build: 2-phase bucket partition ----------------

__global__ __launch_bounds__(256) void partition_k(const int* __restrict__ ei,
                                                   int* __restrict__ bucket_cnt,
                                                   int2* __restrict__ part) {
    __shared__ int hist[K_BUCK];
    __shared__ int goff[K_BUCK];
    const int tid = threadIdx.x;
    for (int i = tid; i < K_BUCK; i += 256) hist[i] = 0;
    __syncthreads();
    const int e0 = blockIdx.x * (256 * P1_EPB);
    int srcv[P1_EPB], dstv[P1_EPB];
    #pragma unroll
    for (int i = 0; i < P1_EPB; ++i) {
        int e = e0 + tid + (i << 8);
        bool ok = e < N_EDGES;
        srcv[i] = ok ? ei[e] : 0;
        dstv[i] = ok ? ei[N_EDGES + e] : -1;
        if (ok) atomicAdd(&hist[dstv[i] >> BUCK_SHIFT], 1);
    }
    __syncthreads();
    for (int b = tid; b < K_BUCK; b += 256) {
        int c = hist[b];
        goff[b] = c ? atomicAdd(&bucket_cnt[b], c) : 0;
        hist[b] = 0;                        // reuse as block-local cursor
    }
    __syncthreads();
    #pragma unroll
    for (int i = 0; i < P1_EPB; ++i) {
        if (dstv[i] >= 0) {
            int b = dstv[i] >> BUCK_SHIFT;
            int pos = goff[b] + atomicAdd(&hist[b], 1);
            if (pos < BUCK_CAP)             // memory-safety guard (statistically impossible)
                part[(size_t)b * BUCK_CAP + pos] = make_int2(srcv[i], dstv[i]);
        }
    }
}

__global__ __launch_bounds__(256) void build_k(const int2* __restrict__ part,
                                               const int* __restrict__ bucket_cnt,
                                               int* __restrict__ rs, int* __restrict__ deg_g,
                                               float* __restrict__ inv, int* __restrict__ csr) {
    __shared__ int degl[128], rsl[128], cur[128];
    __shared__ int wred[4];
    const int b = blockIdx.x;
    const int tid = threadIdx.x, lane = tid & 63, wid = tid >> 6;
    if (tid < 128) degl[tid] = 0;
    // inline exclusive prefix over bucket_cnt[0..b): base for this bucket's csr region
    int psum = 0;
    for (int i = tid; i < b; i += 256) psum += bucket_cnt[i];
    #pragma unroll
    for (int o = 32; o >= 1; o >>= 1) psum += __shfl_xor(psum, o);
    if (lane == 0) wred[wid] = psum;
    __syncthreads();
    const int base = wred[0] + wred[1] + wred[2] + wred[3];
    int Eb = bucket_cnt[b]; if (Eb > BUCK_CAP) Eb = BUCK_CAP;
    const int2* pe = part + (size_t)b * BUCK_CAP;
    for (int i = tid; i < Eb; i += 256)
        atomicAdd(&degl[pe[i].y & 127], 1);
    __syncthreads();
    if (tid < 64) {                          // wave 0 scans 128 counters
        int carry = 0;
        for (int c = 0; c < 128; c += 64) {
            int v = degl[c + tid];
            int sc = v;
            #pragma unroll
            for (int off = 1; off < 64; off <<= 1) {
                int t = __shfl_up(sc, off);
                if (tid >= off) sc += t;
            }
            rsl[c + tid] = carry + sc - v;
            carry += __shfl(sc, 63);
        }
    }
    __syncthreads();
    if (tid < 128) {
        int n = (b << BUCK_SHIFT) + tid;
        if (n < N_NODES) {
            int d = degl[tid];
            rs[n] = base + rsl[tid];
            deg_g[n] = d;
            inv[n] = 1.0f / fmaxf((float)d, 1.0f);
        }
        cur[tid] = 0;
    }
    __syncthreads();
    for (int i = tid; i < Eb; i += 256) {
        int2 e = pe[i];
        int ld = e.y & 127;
        int pos = atomicAdd(&cur[ld], 1);
        csr[base + rsl[ld] + pos] = e.x;    // dense 8KB window, single block
    }
}

// ---------------- aggregation (wide-gather) ----------------

__global__ __launch_bounds__(256) void agg1_k(
        const int* __restrict__ rs, const int* __restrict__ deg,
        const int* __restrict__ csr, const uint* __restrict__ xb,
        const float* __restrict__ inv, uint* __restrict__ cat1) {
    const int wid = threadIdx.x >> 6, lane = threadIdx.x & 63;
    const int n = blockIdx.x * 4 + wid;
    if (n >= N_NODES) return;
    const int g = lane >> 4, sub = lane & 15;
    const int beg = rs[n], cnt = deg[n];
    float a0 = 0.f, a1 = 0.f, a2 = 0.f, a3 = 0.f, a4 = 0.f, a5 = 0.f, a6 = 0.f, a7 = 0.f;
    for (int i0 = 0; i0 < cnt; i0 += 64) {
        int rem = cnt - i0; if (rem > 64) rem = 64;
        int idxv = (lane < rem) ? csr[beg + i0 + lane] : 0;
        int nIter = (rem + 3) >> 2;
        #pragma unroll 4
        for (int i = 0; i < nIter; ++i) {
            int slot = (i << 2) + g;
            int src = __shfl(idxv, slot);
            uint4 v = *(const uint4*)(xb + (size_t)src * 64 + (sub << 2));
            if (slot < rem) {
                a0 += bflo(v.x); a1 += bfhi(v.x);
                a2 += bflo(v.y); a3 += bfhi(v.y);
                a4 += bflo(v.z); a5 += bfhi(v.z);
                a6 += bflo(v.w); a7 += bfhi(v.w);
            }
        }
    }
    a0 += __shfl_xor(a0, 16); a0 += __shfl_xor(a0, 32);
    a1 += __shfl_xor(a1, 16); a1 += __shfl_xor(a1, 32);
    a2 += __shfl_xor(a2, 16); a2 += __shfl_xor(a2, 32);
    a3 += __shfl_xor(a3, 16); a3 += __shfl_xor(a3, 32);
    a4 += __shfl_xor(a4, 16); a4 += __shfl_xor(a4, 32);
    a5 += __shfl_xor(a5, 16); a5 += __shfl_xor(a5, 32);
    a6 += __shfl_xor(a6, 16); a6 += __shfl_xor(a6, 32);
    a7 += __shfl_xor(a7, 16); a7 += __shfl_xor(a7, 32);
    if (g == 0) {
        float w = inv[n];
        uint4 o;
        o.x = pack2(a0 * w, a1 * w);
        o.y = pack2(a2 * w, a3 * w);
        o.z = pack2(a4 * w, a5 * w);
        o.w = pack2(a6 * w, a7 * w);
        *(uint4*)(cat1 + (size_t)n * 128 + (sub << 2)) = o;
    }
    cat1[(size_t)n * 128 + 64 + lane] = xb[(size_t)n * 64 + lane];  // root copy
}

__global__ __launch_bounds__(256) void final_k(
        const int* __restrict__ rs, const int* __restrict__ deg,
        const int* __restrict__ csr, const uint* __restrict__ t2,
        const float* __restrict__ u2, const float* __restrict__ b2,
        const float* __restrict__ inv, float* __restrict__ out) {
    const int wid = threadIdx.x >> 6, lane = threadIdx.x & 63;
    const int n = blockIdx.x * 4 + wid;
    if (n >= N_NODES) return;
    const int g = lane >> 3, sub = lane & 7;
    const int beg = rs[n], cnt = deg[n];
    float a0 = 0.f, a1 = 0.f, a2 = 0.f, a3 = 0.f, a4 = 0.f, a5 = 0.f, a6 = 0.f, a7 = 0.f;
    for (int i0 = 0; i0 < cnt; i0 += 64) {
        int rem = cnt - i0; if (rem > 64) rem = 64;
        int idxv = (lane < rem) ? csr[beg + i0 + lane] : 0;
        int nIter = (rem + 7) >> 3;
        #pragma unroll 4
        for (int i = 0; i < nIter; ++i) {
            int slot = (i << 3) + g;
            int src = __shfl(idxv, slot);
            uint4 v = *(const uint4*)(t2 + (size_t)src * 32 + (sub << 2));
            if (slot < rem) {
                a0 += bflo(v.x); a1 += bfhi(v.x);
                a2 += bflo(v.y); a3 += bfhi(v.y);
                a4 += bflo(v.z); a5 += bfhi(v.z);
                a6 += bflo(v.w); a7 += bfhi(v.w);
            }
        }
    }
    a0 += __shfl_xor(a0, 8); a0 += __shfl_xor(a0, 16); a0 += __shfl_xor(a0, 32);
    a1 += __shfl_xor(a1, 8); a1 += __shfl_xor(a1, 16); a1 += __shfl_xor(a1, 32);
    a2 += __shfl_xor(a2, 8); a2 += __shfl_xor(a2, 16); a2 += __shfl_xor(a2, 32);
    a3 += __shfl_xor(a3, 8); a3 += __shfl_xor(a3, 16); a3 += __shfl_xor(a3, 32);
    a4 += __shfl_xor(a4, 8); a4 += __shfl_xor(a4, 16); a4 += __shfl_xor(a4, 32);
    a5 += __shfl_xor(a5, 8); a5 += __shfl_xor(a5, 16); a5 += __shfl_xor(a5, 32);
    a6 += __shfl_xor(a6, 8); a6 += __shfl_xor(a6, 16); a6 += __shfl_xor(a6, 32);
    a7 += __shfl_xor(a7, 8); a7 += __shfl_xor(a7, 16); a7 += __shfl_xor(a7, 32);
    if (g == 0) {
        float w = inv[n];
        const float* ur = u2 + (size_t)n * 64 + (sub << 3);
        float4 u0 = *(const float4*)ur;
        float4 u1 = *(const float4*)(ur + 4);
        const float* br = b2 + (sub << 3);
        float4 o0, o1;
        o0.x = u0.x + br[0] + a0 * w; o0.y = u0.y + br[1] + a1 * w;
        o0.z = u0.z + br[2] + a2 * w; o0.w = u0.w + br[3] + a3 * w;
        o1.x = u1.x + br[4] + a4 * w; o1.y = u1.y + br[5] + a5 * w;
        o1.z = u1.z + br[6] + a6 * w; o1.w = u1.w + br[7] + a7 * w;
        float* orow = out + (size_t)n * 64 + (sub << 3);
        *(float4*)orow = o0;
        *(float4*)(orow + 4) = o1;
    }
}

// ---------------- fused gemm12: h1 lives in LDS only ----------------
// grid = 391 (one 128-row tile), 512 threads = 8 waves.
// Per half h in {0,1}:
//   phase 1: Hh = relu(cat1_tile @ B1[h*128..+128]^T + b1)   (128x128, MFMA, acc1)
//            -> parked bf16 in Hs[128][136] (pad breaks phase-2 bank conflict)
//   phase 2: acc2 += Hs @ B2[:, h*128..+128]^T               (128x128, all K in LDS)
// Epilogue: cols 0..63 -> t2 bf16, 64..127 -> u2 fp32.
// LDS: Hs 34 KB + As 8 KB + Bs 8 KB = 50 KB -> ~2 blocks/CU; 391 blocks = 1 round.

#define HS_OFF 0
#define HS_STRIDE 136
#define AS_OFF 17408
#define BS_OFF 21504

__global__ __launch_bounds__(512) void gemm12_k(const ushort* __restrict__ A,
                                                const ushort* __restrict__ B1,
                                                const ushort* __restrict__ B2,
                                                const float* __restrict__ b1,
                                                ushort* __restrict__ t2,
                                                float* __restrict__ u2) {
    __shared__ __align__(16) ushort lds[25600];
    const int bm = blockIdx.x * 128;
    const int tid = threadIdx.x;
    const int w = tid >> 6, lane = tid & 63;
    const int q = lane >> 4, mr = lane & 15;
    const int wm = (w & 1) << 6;          // wave rows 0/64
    const int wn = (w >> 1) << 5;         // wave cols 0/32/64/96 (within 128)
    const int srow = tid >> 2;            // staging row 0..127
    const int scol = (tid & 3) << 3;      // staging ushort offset (16B granules)

    floatx4 acc2[4][2];
    #pragma unroll
    for (int i = 0; i < 4; ++i)
        #pragma unroll
        for (int j = 0; j < 2; ++j)
            acc2[i][j] = (floatx4){0.f, 0.f, 0.f, 0.f};

    #pragma unroll
    for (int h = 0; h < 2; ++h) {
        // ---- phase 1: acc1 = cat1_tile @ B1half^T ----
        floatx4 acc1[4][2];
        #pragma unroll
        for (int i = 0; i < 4; ++i)
            #pragma unroll
            for (int j = 0; j < 2; ++j)
                acc1[i][j] = (floatx4){0.f, 0.f, 0.f, 0.f};
        for (int k0 = 0; k0 < 256; k0 += 32) {
            gload_lds16(A + (size_t)(bm + srow) * 256 + k0 + scol,
                        lds + AS_OFF + srow * 32 + scol);
            gload_lds16(B1 + (size_t)(h * 128 + srow) * 256 + k0 + scol,
                        lds + BS_OFF + srow * 32 + scol);
            __syncthreads();
            short8 af[4], bfr[2];
            #pragma unroll
            for (int i = 0; i < 4; ++i)
                af[i] = *(const short8*)&lds[AS_OFF + (wm + (i << 4) + mr) * 32 + (q << 3)];
            #pragma unroll
            for (int j = 0; j < 2; ++j)
                bfr[j] = *(const short8*)&lds[BS_OFF + (wn + (j << 4) + mr) * 32 + (q << 3)];
            #pragma unroll
            for (int i = 0; i < 4; ++i)
                #pragma unroll
                for (int j = 0; j < 2; ++j)
                    acc1[i][j] = __builtin_amdgcn_mfma_f32_16x16x32_bf16(af[i], bfr[j], acc1[i][j], 0, 0, 0);
            __syncthreads();
        }
        // ---- epilogue 1: relu+bias -> Hs (bf16) ----
        #pragma unroll
        for (int i = 0; i < 4; ++i) {
            int row = wm + (i << 4) + (q << 2);
            #pragma unroll
            for (int j = 0; j < 2; ++j) {
                int col = wn + (j << 4) + mr;
                float bv = b1[h * 128 + col];
                #pragma unroll
                for (int r = 0; r < 4; ++r) {
                    float v = fmaxf(acc1[i][j][r] + bv, 0.f);
                    lds[HS_OFF + (row + r) * HS_STRIDE + col] = f2bf(v);
                }
            }
        }
        __syncthreads();
        // ---- phase 2: acc2 += Hs @ B2[:, h*128..]^T ----
        for (int kk = 0; kk < 128; kk += 32) {
            gload_lds16(B2 + (size_t)srow * 256 + h * 128 + kk + scol,
                        lds + AS_OFF + srow * 32 + scol);   // reuse As region
            __syncthreads();
            short8 af2[4], bf2[2];
            #pragma unroll
            for (int i = 0; i < 4; ++i)
                af2[i] = *(const short8*)&lds[HS_OFF + (wm + (i << 4) + mr) * HS_STRIDE + kk + (q << 3)];
            #pragma unroll
            for (int j = 0; j < 2; ++j)
                bf2[j] = *(const short8*)&lds[AS_OFF + (wn + (j << 4) + mr) * 32 + (q << 3)];
            #pragma unroll
            for (int i = 0; i < 4; ++i)
                #pragma unroll
                for (int j = 0; j < 2; ++j)
                    acc2[i][j] = __builtin_amdgcn_mfma_f32_16x16x32_bf16(af2[i], bf2[j], acc2[i][j], 0, 0, 0);
            __syncthreads();
        }
    }
    // ---- epilogue 2: t2 (cols 0..63, bf16) | u2 (cols 64..127, fp32) ----
    #pragma unroll
    for (int i = 0; i < 4; ++i) {
        int row = bm + wm + (i << 4) + (q << 2);
        #pragma unroll
        for (int j = 0; j < 2; ++j) {
            int col = wn + (j << 4) + mr;
            #pragma unroll
            for (int r = 0; r < 4; ++r) {
                float v = acc2[i][j][r];
                if (col < 64) t2[(size_t)(row + r) * 64 + col] = f2bf(v);
                else          u2[(size_t)(row + r) * 64 + (col - 64)] = v;
            }
        }
    }
}

// ---------------- launch ----------------

extern "C" void kernel_launch(void* const* d_in, const int* in_sizes, int n_in,
                              void* d_out, int out_size, void* d_ws, size_t ws_size,
                              hipStream_t stream) {
    const float* x   = (const float*)d_in[0];
    const int*   ei  = (const int*)d_in[1];
    const float* W1l = (const float*)d_in[2];
    const float* W1r = (const float*)d_in[3];
    const float* b1  = (const float*)d_in[4];
    const float* W2l = (const float*)d_in[5];
    const float* W2r = (const float*)d_in[6];
    const float* b2  = (const float*)d_in[7];
    float* out = (float*)d_out;

    char* base = (char*)d_ws;
    size_t off = 0;
    auto alloc = [&](size_t bytes) -> void* {
        void* p = base + off;
        off = (off + bytes + 255) & ~(size_t)255;
        return p;
    };
    int*    deg        = (int*)alloc(M_PAD * 4);
    int*    rs         = (int*)alloc(M_PAD * 4);
    float*  inv        = (float*)alloc(M_PAD * 4);
    int*    bucket_cnt = (int*)alloc(K_BUCK * 4);
    int*    csr        = (int*)alloc((size_t)N_EDGES * 4);
    int2*   part       = (int2*)alloc((size_t)K_BUCK * BUCK_CAP * 8);
    uint*   xb         = (uint*)alloc((size_t)N_NODES * 64 * 4);
    uint*   cat1       = (uint*)alloc((size_t)M_PAD * 128 * 4);
    uint*   t2         = (uint*)alloc((size_t)M_PAD * 32 * 4);
    float*  u2         = (float*)alloc((size_t)M_PAD * 64 * 4);
    ushort* B1         = (ushort*)alloc(256 * 256 * 2);
    ushort* B2         = (ushort*)alloc(128 * 256 * 2);

    prep_k<<<(N_NODES * 64 + 98304 + K_BUCK + 255) / 256, 256, 0, stream>>>(
        (const float2*)x, xb, W1l, W1r, W2l, W2r, B1, B2, bucket_cnt);

    partition_k<<<(N_EDGES + 256 * P1_EPB - 1) / (256 * P1_EPB), 256, 0, stream>>>(
        ei, bucket_cnt, part);
    build_k<<<K_BUCK, 256, 0, stream>>>(part, bucket_cnt, rs, deg, inv, csr);

    agg1_k<<<(N_NODES + 3) / 4, 256, 0, stream>>>(rs, deg, csr, xb, inv, cat1);

    gemm12_k<<<K_BUCK, 512, 0, stream>>>((const ushort*)cat1, B1, B2, b1,
                                         (ushort*)t2, u2);

    final_k<<<(N_NODES + 3) / 4, 256, 0, stream>>>(rs, deg, csr, t2, u2, b2, inv, out);
}

// Round 6
// 186.731 us; speedup vs baseline: 2.7085x; 1.0623x over previous
//
#include <hip/hip_runtime.h>
#include <hip/hip_bf16.h>

// GraphSAGE 2-layer forward, bf16-MFMA inner pipeline.
// R6: 2-node-interleaved agg1 / 4-node-interleaved final (2-4x memory-level
//     parallelism in the latency-bound gathers), prep merged into partition
//     (one serialization point fewer), part[] packed to int, u2 in bf16.
// Dispatches: memset(1.5KB) -> entry(partition+prep) -> build -> agg1 -> gemm12 -> final.

#define N_NODES 50000
#define N_EDGES 800000
#define M_PAD   50048   // 391 * 128

#define BUCK_SHIFT 7
#define K_BUCK 391            // ceil(50000/128)
#define BUCK_CAP 4096         // bucket edges: mean 2046, sigma ~45 (guarded anyway)
#define P1_EPB 16             // edges per thread in partition phase (4096/block)
#define P_BLOCKS 196          // ceil(800000/4096)
#define PREP_ELEMS (N_NODES * 64 + 98304)   // 3298304 = 12884*256 exactly

typedef unsigned int uint;
typedef unsigned short ushort;
typedef __attribute__((ext_vector_type(8))) short short8;
typedef __attribute__((ext_vector_type(4))) float floatx4;

__device__ __forceinline__ ushort f2bf(float f) {
    union { float f; uint u; } c; c.f = f;
    uint u = c.u;
    return (ushort)((u + 0x7FFFu + ((u >> 16) & 1u)) >> 16);  // RNE
}
__device__ __forceinline__ uint pack2(float lo, float hi) {
    return (uint)f2bf(lo) | ((uint)f2bf(hi) << 16);
}
__device__ __forceinline__ float bflo(uint v) { return __uint_as_float(v << 16); }
__device__ __forceinline__ float bfhi(uint v) { return __uint_as_float(v & 0xffff0000u); }
__device__ __forceinline__ void gload_lds16(const ushort* g, ushort* l) {
    __builtin_amdgcn_global_load_lds(
        (const __attribute__((address_space(1))) void*)g,
        (__attribute__((address_space(3))) void*)l, 16, 0, 0);
}

#define ACC8(A, v) { A[0] += bflo(v.x); A[1] += bfhi(v.x); A[2] += bflo(v.y); A[3] += bfhi(v.y); \
                     A[4] += bflo(v.z); A[5] += bfhi(v.z); A[6] += bflo(v.w); A[7] += bfhi(v.w); }

// ---------------- entry: partition (blocks < P_BLOCKS) + dtype prep ----------------

__global__ __launch_bounds__(256) void entry_k(
        const int* __restrict__ ei, int* __restrict__ bucket_cnt, int* __restrict__ part,
        const float2* __restrict__ x2, uint* __restrict__ xb,
        const float* __restrict__ W1l, const float* __restrict__ W1r,
        const float* __restrict__ W2l, const float* __restrict__ W2r,
        ushort* __restrict__ B1, ushort* __restrict__ B2) {
    __shared__ int hist[K_BUCK];
    __shared__ int goff[K_BUCK];
    const int tid = threadIdx.x;
    if (blockIdx.x < P_BLOCKS) {
        // ---- partition: LDS histogram + per-(block,bucket) reservation ----
        for (int i = tid; i < K_BUCK; i += 256) hist[i] = 0;
        __syncthreads();
        const int e0 = blockIdx.x * (256 * P1_EPB);
        int srcv[P1_EPB], dstv[P1_EPB];
        #pragma unroll
        for (int i = 0; i < P1_EPB; ++i) {
            int e = e0 + tid + (i << 8);
            bool ok = e < N_EDGES;
            srcv[i] = ok ? ei[e] : 0;
            dstv[i] = ok ? ei[N_EDGES + e] : -1;
            if (ok) atomicAdd(&hist[dstv[i] >> BUCK_SHIFT], 1);
        }
        __syncthreads();
        for (int b = tid; b < K_BUCK; b += 256) {
            int c = hist[b];
            goff[b] = c ? atomicAdd(&bucket_cnt[b], c) : 0;
            hist[b] = 0;                    // reuse as block-local cursor
        }
        __syncthreads();
        #pragma unroll
        for (int i = 0; i < P1_EPB; ++i) {
            if (dstv[i] >= 0) {
                int b = dstv[i] >> BUCK_SHIFT;
                int pos = goff[b] + atomicAdd(&hist[b], 1);
                if (pos < BUCK_CAP)         // memory-safety guard
                    part[(size_t)b * BUCK_CAP + pos] = srcv[i] | ((dstv[i] & 127) << 16);
            }
        }
        return;
    }
    // ---- prep: x -> bf16, weights -> [N][K] bf16 ----
    int i = (blockIdx.x - P_BLOCKS) * 256 + tid;
    if (i < N_NODES * 64) {
        float2 v = x2[i];
        xb[i] = pack2(v.x, v.y);
        return;
    }
    int t = i - N_NODES * 64;
    if (t < 65536) {                        // B1[n][k], n<256, k<256
        int n = t >> 8, k = t & 255;
        float v = (k < 128) ? W1l[n * 128 + k] : W1r[n * 128 + (k - 128)];
        B1[t] = f2bf(v);
    } else if (t < 98304) {                 // B2[n][k], n<128, k<256
        int t2 = t - 65536;
        int n = t2 >> 8, k = t2 & 255;
        float v = (n < 64) ? W2l[n * 256 + k] : W2r[(n - 64) * 256 + k];
        B2[t2] = f2bf(v);
    }
}

// ---------------- build: per-bucket LDS degree/scan/cursor -> csr ----------------

__global__ __launch_bounds__(256) void build_k(const int* __restrict__ part,
                                               const int* __restrict__ bucket_cnt,
                                               int* __restrict__ rs, int* __restrict__ deg_g,
                                               float* __restrict__ inv, int* __restrict__ csr) {
    __shared__ int degl[128], rsl[128], cur[128];
    __shared__ int wred[4];
    const int b = blockIdx.x;
    const int tid = threadIdx.x, lane = tid & 63, wid = tid >> 6;
    if (tid < 128) degl[tid] = 0;
    // inline exclusive prefix over bucket_cnt[0..b)
    int psum = 0;
    for (int i = tid; i < b; i += 256) psum += bucket_cnt[i];
    #pragma unroll
    for (int o = 32; o >= 1; o >>= 1) psum += __shfl_xor(psum, o);
    if (lane == 0) wred[wid] = psum;
    __syncthreads();
    const int base = wred[0] + wred[1] + wred[2] + wred[3];
    int Eb = bucket_cnt[b]; if (Eb > BUCK_CAP) Eb = BUCK_CAP;
    const int* pe = part + (size_t)b * BUCK_CAP;
    for (int i = tid; i < Eb; i += 256)
        atomicAdd(&degl[pe[i] >> 16], 1);
    __syncthreads();
    if (tid < 64) {                          // wave 0 scans 128 counters
        int carry = 0;
        for (int c = 0; c < 128; c += 64) {
            int v = degl[c + tid];
            int sc = v;
            #pragma unroll
            for (int off = 1; off < 64; off <<= 1) {
                int t = __shfl_up(sc, off);
                if (tid >= off) sc += t;
            }
            rsl[c + tid] = carry + sc - v;
            carry += __shfl(sc, 63);
        }
    }
    __syncthreads();
    if (tid < 128) {
        int n = (b << BUCK_SHIFT) + tid;
        if (n < N_NODES) {
            int d = degl[tid];
            rs[n] = base + rsl[tid];
            deg_g[n] = d;
            inv[n] = 1.0f / fmaxf((float)d, 1.0f);
        }
        cur[tid] = 0;
    }
    __syncthreads();
    for (int i = tid; i < Eb; i += 256) {
        int e = pe[i];
        int ld = e >> 16;
        int pos = atomicAdd(&cur[ld], 1);
        csr[base + rsl[ld] + pos] = e & 0xFFFF;   // dense 8KB window
    }
}

// ---------------- agg1: 2 nodes per wave, interleaved gather chains ----------------
// Row = 64 uints = 16 lanes x uint4; lane-group g=lane>>4 handles slot i*4+g for BOTH
// nodes -> 8 loads in flight per lane. grid = ceil(N/8), 4 waves/block.

__global__ __launch_bounds__(256) void agg1_k(
        const int* __restrict__ rs, const int* __restrict__ deg,
        const int* __restrict__ csr, const uint* __restrict__ xb,
        const float* __restrict__ inv, uint* __restrict__ cat1) {
    const int wid = threadIdx.x >> 6, lane = threadIdx.x & 63;
    const int n0 = blockIdx.x * 8 + wid * 2;
    if (n0 >= N_NODES) return;
    const bool has1 = (n0 + 1) < N_NODES;
    const int g = lane >> 4, sub = lane & 15;
    const int beg0 = rs[n0], cnt0 = deg[n0];
    const int beg1 = has1 ? rs[n0 + 1] : 0, cnt1 = has1 ? deg[n0 + 1] : 0;
    float A0[8] = {}, A1[8] = {};
    if (cnt0 <= 64 && cnt1 <= 64) {
        int idx0 = (lane < cnt0) ? csr[beg0 + lane] : 0;
        int idx1 = (lane < cnt1) ? csr[beg1 + lane] : 0;
        int maxc = cnt0 > cnt1 ? cnt0 : cnt1;
        int nI = (maxc + 3) >> 2;
        #pragma unroll 4
        for (int i = 0; i < nI; ++i) {
            int slot = (i << 2) + g;
            int s0 = __shfl(idx0, slot);
            int s1 = __shfl(idx1, slot);
            uint4 v0 = *(const uint4*)(xb + (size_t)s0 * 64 + (sub << 2));
            uint4 v1 = *(const uint4*)(xb + (size_t)s1 * 64 + (sub << 2));
            if (slot < cnt0) ACC8(A0, v0);
            if (slot < cnt1) ACC8(A1, v1);
        }
    } else {                                 // deg>64 fallback (essentially never)
        for (int i0 = 0; i0 < cnt0; i0 += 64) {
            int rem = cnt0 - i0; if (rem > 64) rem = 64;
            int idxv = (lane < rem) ? csr[beg0 + i0 + lane] : 0;
            int nI = (rem + 3) >> 2;
            for (int i = 0; i < nI; ++i) {
                int slot = (i << 2) + g;
                int s = __shfl(idxv, slot);
                uint4 v = *(const uint4*)(xb + (size_t)s * 64 + (sub << 2));
                if (slot < rem) ACC8(A0, v);
            }
        }
        for (int i0 = 0; i0 < cnt1; i0 += 64) {
            int rem = cnt1 - i0; if (rem > 64) rem = 64;
            int idxv = (lane < rem) ? csr[beg1 + i0 + lane] : 0;
            int nI = (rem + 3) >> 2;
            for (int i = 0; i < nI; ++i) {
                int slot = (i << 2) + g;
                int s = __shfl(idxv, slot);
                uint4 v = *(const uint4*)(xb + (size_t)s * 64 + (sub << 2));
                if (slot < rem) ACC8(A1, v);
            }
        }
    }
    #pragma unroll
    for (int c = 0; c < 8; ++c) {
        A0[c] += __shfl_xor(A0[c], 16); A0[c] += __shfl_xor(A0[c], 32);
        A1[c] += __shfl_xor(A1[c], 16); A1[c] += __shfl_xor(A1[c], 32);
    }
    if (g == 0) {
        float w = inv[n0];
        uint4 o;
        o.x = pack2(A0[0] * w, A0[1] * w); o.y = pack2(A0[2] * w, A0[3] * w);
        o.z = pack2(A0[4] * w, A0[5] * w); o.w = pack2(A0[6] * w, A0[7] * w);
        *(uint4*)(cat1 + (size_t)n0 * 128 + (sub << 2)) = o;
    } else if (g == 1 && has1) {
        float w = inv[n0 + 1];
        uint4 o;
        o.x = pack2(A1[0] * w, A1[1] * w); o.y = pack2(A1[2] * w, A1[3] * w);
        o.z = pack2(A1[4] * w, A1[5] * w); o.w = pack2(A1[6] * w, A1[7] * w);
        *(uint4*)(cat1 + (size_t)(n0 + 1) * 128 + (sub << 2)) = o;
    }
    cat1[(size_t)n0 * 128 + 64 + lane] = xb[(size_t)n0 * 64 + lane];      // root copies
    if (has1)
        cat1[(size_t)(n0 + 1) * 128 + 64 + lane] = xb[(size_t)(n0 + 1) * 64 + lane];
}

// ---------------- final: 4 nodes per wave ----------------
// t2 row = 32 uints = 8 lanes x uint4; group g=lane>>3 handles slot i*8+g for 4 nodes.

__global__ __launch_bounds__(256) void final_k(
        const int* __restrict__ rs, const int* __restrict__ deg,
        const int* __restrict__ csr, const uint* __restrict__ t2,
        const uint* __restrict__ u2, const float* __restrict__ b2,
        const float* __restrict__ inv, float* __restrict__ out) {
    const int wid = threadIdx.x >> 6, lane = threadIdx.x & 63;
    const int base = blockIdx.x * 16 + wid * 4;
    if (base >= N_NODES) return;
    const int g = lane >> 3, sub = lane & 7;
    int begj[4], cntj[4];
    #pragma unroll
    for (int j = 0; j < 4; ++j) {
        bool ok = (base + j) < N_NODES;
        begj[j] = ok ? rs[base + j] : 0;
        cntj[j] = ok ? deg[base + j] : 0;
    }
    float A[4][8] = {};
    bool fast = cntj[0] <= 64 && cntj[1] <= 64 && cntj[2] <= 64 && cntj[3] <= 64;
    if (fast) {
        int idxr[4];
        #pragma unroll
        for (int j = 0; j < 4; ++j)
            idxr[j] = (lane < cntj[j]) ? csr[begj[j] + lane] : 0;
        int maxc = cntj[0];
        #pragma unroll
        for (int j = 1; j < 4; ++j) maxc = cntj[j] > maxc ? cntj[j] : maxc;
        int nI = (maxc + 7) >> 3;
        #pragma unroll 2
        for (int i = 0; i < nI; ++i) {
            int slot = (i << 3) + g;
            int s[4];
            #pragma unroll
            for (int j = 0; j < 4; ++j) s[j] = __shfl(idxr[j], slot);
            uint4 v[4];
            #pragma unroll
            for (int j = 0; j < 4; ++j)
                v[j] = *(const uint4*)(t2 + (size_t)s[j] * 32 + (sub << 2));
            if (slot < cntj[0]) ACC8(A[0], v[0]);
            if (slot < cntj[1]) ACC8(A[1], v[1]);
            if (slot < cntj[2]) ACC8(A[2], v[2]);
            if (slot < cntj[3]) ACC8(A[3], v[3]);
        }
    } else {                                 // deg>64 fallback
        #pragma unroll
        for (int j = 0; j < 4; ++j) {
            for (int i0 = 0; i0 < cntj[j]; i0 += 64) {
                int rem = cntj[j] - i0; if (rem > 64) rem = 64;
                int idxv = (lane < rem) ? csr[begj[j] + i0 + lane] : 0;
                int nI = (rem + 7) >> 3;
                for (int i = 0; i < nI; ++i) {
                    int slot = (i << 3) + g;
                    int s = __shfl(idxv, slot);
                    uint4 v = *(const uint4*)(t2 + (size_t)s * 32 + (sub << 2));
                    if (slot < rem) ACC8(A[j], v);
                }
            }
        }
    }
    #pragma unroll
    for (int j = 0; j < 4; ++j)
        #pragma unroll
        for (int c = 0; c < 8; ++c) {
            A[j][c] += __shfl_xor(A[j][c], 8);
            A[j][c] += __shfl_xor(A[j][c], 16);
            A[j][c] += __shfl_xor(A[j][c], 32);
        }
    #pragma unroll
    for (int j = 0; j < 4; ++j) {
        int n = base + j;
        if (g == j && n < N_NODES) {
            float w = inv[n];
            uint4 ur = *(const uint4*)(u2 + (size_t)n * 32 + (sub << 2));
            const float* br = b2 + (sub << 3);
            float4 o0, o1;
            o0.x = bflo(ur.x) + br[0] + A[j][0] * w;
            o0.y = bfhi(ur.x) + br[1] + A[j][1] * w;
            o0.z = bflo(ur.y) + br[2] + A[j][2] * w;
            o0.w = bfhi(ur.y) + br[3] + A[j][3] * w;
            o1.x = bflo(ur.z) + br[4] + A[j][4] * w;
            o1.y = bfhi(ur.z) + br[5] + A[j][5] * w;
            o1.z = bflo(ur.w) + br[6] + A[j][6] * w;
            o1.w = bfhi(ur.w) + br[7] + A[j][7] * w;
            float* orow = out + (size_t)n * 64 + (sub << 3);
            *(float4*)orow = o0;
            *(float4*)(orow + 4) = o1;
        }
    }
}

// ---------------- fused gemm12: h1 lives in LDS only ----------------

#define HS_OFF 0
#define HS_STRIDE 136
#define AS_OFF 17408
#define BS_OFF 21504

__global__ __launch_bounds__(512) void gemm12_k(const ushort* __restrict__ A,
                                                const ushort* __restrict__ B1,
                                                const ushort* __restrict__ B2,
                                                const float* __restrict__ b1,
                                                ushort* __restrict__ t2,
                                                ushort* __restrict__ u2b) {
    __shared__ __align__(16) ushort lds[25600];
    const int bm = blockIdx.x * 128;
    const int tid = threadIdx.x;
    const int w = tid >> 6, lane = tid & 63;
    const int q = lane >> 4, mr = lane & 15;
    const int wm = (w & 1) << 6;
    const int wn = (w >> 1) << 5;
    const int srow = tid >> 2;
    const int scol = (tid & 3) << 3;

    floatx4 acc2[4][2];
    #pragma unroll
    for (int i = 0; i < 4; ++i)
        #pragma unroll
        for (int j = 0; j < 2; ++j)
            acc2[i][j] = (floatx4){0.f, 0.f, 0.f, 0.f};

    #pragma unroll
    for (int h = 0; h < 2; ++h) {
        floatx4 acc1[4][2];
        #pragma unroll
        for (int i = 0; i < 4; ++i)
            #pragma unroll
            for (int j = 0; j < 2; ++j)
                acc1[i][j] = (floatx4){0.f, 0.f, 0.f, 0.f};
        for (int k0 = 0; k0 < 256; k0 += 32) {
            gload_lds16(A + (size_t)(bm + srow) * 256 + k0 + scol,
                        lds + AS_OFF + srow * 32 + scol);
            gload_lds16(B1 + (size_t)(h * 128 + srow) * 256 + k0 + scol,
                        lds + BS_OFF + srow * 32 + scol);
            __syncthreads();
            short8 af[4], bfr[2];
            #pragma unroll
            for (int i = 0; i < 4; ++i)
                af[i] = *(const short8*)&lds[AS_OFF + (wm + (i << 4) + mr) * 32 + (q << 3)];
            #pragma unroll
            for (int j = 0; j < 2; ++j)
                bfr[j] = *(const short8*)&lds[BS_OFF + (wn + (j << 4) + mr) * 32 + (q << 3)];
            #pragma unroll
            for (int i = 0; i < 4; ++i)
                #pragma unroll
                for (int j = 0; j < 2; ++j)
                    acc1[i][j] = __builtin_amdgcn_mfma_f32_16x16x32_bf16(af[i], bfr[j], acc1[i][j], 0, 0, 0);
            __syncthreads();
        }
        #pragma unroll
        for (int i = 0; i < 4; ++i) {
            int row = wm + (i << 4) + (q << 2);
            #pragma unroll
            for (int j = 0; j < 2; ++j) {
                int col = wn + (j << 4) + mr;
                float bv = b1[h * 128 + col];
                #pragma unroll
                for (int r = 0; r < 4; ++r) {
                    float v = fmaxf(acc1[i][j][r] + bv, 0.f);
                    lds[HS_OFF + (row + r) * HS_STRIDE + col] = f2bf(v);
                }
            }
        }
        __syncthreads();
        for (int kk = 0; kk < 128; kk += 32) {
            gload_lds16(B2 + (size_t)srow * 256 + h * 128 + kk + scol,
                        lds + AS_OFF + srow * 32 + scol);
            __syncthreads();
            short8 af2[4], bf2[2];
            #pragma unroll
            for (int i = 0; i < 4; ++i)
                af2[i] = *(const short8*)&lds[HS_OFF + (wm + (i << 4) + mr) * HS_STRIDE + kk + (q << 3)];
            #pragma unroll
            for (int j = 0; j < 2; ++j)
                bf2[j] = *(const short8*)&lds[AS_OFF + (wn + (j << 4) + mr) * 32 + (q << 3)];
            #pragma unroll
            for (int i = 0; i < 4; ++i)
                #pragma unroll
                for (int j = 0; j < 2; ++j)
                    acc2[i][j] = __builtin_amdgcn_mfma_f32_16x16x32_bf16(af2[i], bf2[j], acc2[i][j], 0, 0, 0);
            __syncthreads();
        }
    }
    #pragma unroll
    for (int i = 0; i < 4; ++i) {
        int row = bm + wm + (i << 4) + (q << 2);
        #pragma unroll
        for (int j = 0; j < 2; ++j) {
            int col = wn + (j << 4) + mr;
            #pragma unroll
            for (int r = 0; r < 4; ++r) {
                float v = acc2[i][j][r];
                if (col < 64) t2[(size_t)(row + r) * 64 + col] = f2bf(v);
                else          u2b[(size_t)(row + r) * 64 + (col - 64)] = f2bf(v);
            }
        }
    }
}

// ---------------- launch ----------------

extern "C" void kernel_launch(void* const* d_in, const int* in_sizes, int n_in,
                              void* d_out, int out_size, void* d_ws, size_t ws_size,
                              hipStream_t stream) {
    const float* x   = (const float*)d_in[0];
    const int*   ei  = (const int*)d_in[1];
    const float* W1l = (const float*)d_in[2];
    const float* W1r = (const float*)d_in[3];
    const float* b1  = (const float*)d_in[4];
    const float* W2l = (const float*)d_in[5];
    const float* W2r = (const float*)d_in[6];
    const float* b2  = (const float*)d_in[7];
    float* out = (float*)d_out;

    char* base = (char*)d_ws;
    size_t off = 0;
    auto alloc = [&](size_t bytes) -> void* {
        void* p = base + off;
        off = (off + bytes + 255) & ~(size_t)255;
        return p;
    };
    int*    deg        = (int*)alloc(M_PAD * 4);
    int*    rs         = (int*)alloc(M_PAD * 4);
    float*  inv        = (float*)alloc(M_PAD * 4);
    int*    bucket_cnt = (int*)alloc(K_BUCK * 4);
    int*    csr        = (int*)alloc((size_t)N_EDGES * 4);
    int*    part       = (int*)alloc((size_t)K_BUCK * BUCK_CAP * 4);
    uint*   xb         = (uint*)alloc((size_t)N_NODES * 64 * 4);
    uint*   cat1       = (uint*)alloc((size_t)M_PAD * 128 * 4);
    uint*   t2         = (uint*)alloc((size_t)M_PAD * 32 * 4);
    uint*   u2         = (uint*)alloc((size_t)M_PAD * 32 * 4);
    ushort* B1         = (ushort*)alloc(256 * 256 * 2);
    ushort* B2         = (ushort*)alloc(128 * 256 * 2);

    hipMemsetAsync(bucket_cnt, 0, K_BUCK * sizeof(int), stream);

    entry_k<<<P_BLOCKS + PREP_ELEMS / 256, 256, 0, stream>>>(
        ei, bucket_cnt, part, (const float2*)x, xb, W1l, W1r, W2l, W2r, B1, B2);

    build_k<<<K_BUCK, 256, 0, stream>>>(part, bucket_cnt, rs, deg, inv, csr);

    agg1_k<<<(N_NODES + 7) / 8, 256, 0, stream>>>(rs, deg, csr, xb, inv, cat1);

    gemm12_k<<<K_BUCK, 512, 0, stream>>>((const ushort*)cat1, B1, B2, b1,
                                         (ushort*)t2, (ushort*)u2);

    final_k<<<(N_NODES + 15) / 16, 256, 0, stream>>>(rs, deg, csr, t2, u2, b2, inv, out);
}

// Round 7
// 183.634 us; speedup vs baseline: 2.7542x; 1.0169x over previous
//
#include <hip/hip_runtime.h>
#include <hip/hip_bf16.h>

// GraphSAGE 2-layer forward, bf16-MFMA inner pipeline.
// R7: gemm12 restructured — BK=64 dual-panel staging, phase-2 B2-half staged once
//     (50 -> 20 barriers/block), B2 DMA overlapped with Hs epilogue; cat1 root-copy
//     eliminated (gemm12 A-tile staged from aggb for k<128 and xb for k>=128).
// Dispatches: memset(1.5KB) -> entry(partition+prep) -> build -> agg1 -> gemm12 -> final.

#define N_NODES 50000
#define N_EDGES 800000
#define M_PAD   50048   // 391 * 128

#define BUCK_SHIFT 7
#define K_BUCK 391            // ceil(50000/128)
#define BUCK_CAP 4096         // bucket edges: mean 2046, sigma ~45 (guarded anyway)
#define P1_EPB 16             // edges per thread in partition phase (4096/block)
#define P_BLOCKS 196          // ceil(800000/4096)
#define PREP_ELEMS (N_NODES * 64 + 98304)   // 3298304 = 12884*256 exactly

typedef unsigned int uint;
typedef unsigned short ushort;
typedef __attribute__((ext_vector_type(8))) short short8;
typedef __attribute__((ext_vector_type(4))) float floatx4;

__device__ __forceinline__ ushort f2bf(float f) {
    union { float f; uint u; } c; c.f = f;
    uint u = c.u;
    return (ushort)((u + 0x7FFFu + ((u >> 16) & 1u)) >> 16);  // RNE
}
__device__ __forceinline__ uint pack2(float lo, float hi) {
    return (uint)f2bf(lo) | ((uint)f2bf(hi) << 16);
}
__device__ __forceinline__ float bflo(uint v) { return __uint_as_float(v << 16); }
__device__ __forceinline__ float bfhi(uint v) { return __uint_as_float(v & 0xffff0000u); }
__device__ __forceinline__ void gload_lds16(const ushort* g, ushort* l) {
    __builtin_amdgcn_global_load_lds(
        (const __attribute__((address_space(1))) void*)g,
        (__attribute__((address_space(3))) void*)l, 16, 0, 0);
}

#define ACC8(A, v) { A[0] += bflo(v.x); A[1] += bfhi(v.x); A[2] += bflo(v.y); A[3] += bfhi(v.y); \
                     A[4] += bflo(v.z); A[5] += bfhi(v.z); A[6] += bflo(v.w); A[7] += bfhi(v.w); }

// ---------------- entry: partition (blocks < P_BLOCKS) + dtype prep ----------------

__global__ __launch_bounds__(256) void entry_k(
        const int* __restrict__ ei, int* __restrict__ bucket_cnt, int* __restrict__ part,
        const float2* __restrict__ x2, uint* __restrict__ xb,
        const float* __restrict__ W1l, const float* __restrict__ W1r,
        const float* __restrict__ W2l, const float* __restrict__ W2r,
        ushort* __restrict__ B1, ushort* __restrict__ B2) {
    __shared__ int hist[K_BUCK];
    __shared__ int goff[K_BUCK];
    const int tid = threadIdx.x;
    if (blockIdx.x < P_BLOCKS) {
        for (int i = tid; i < K_BUCK; i += 256) hist[i] = 0;
        __syncthreads();
        const int e0 = blockIdx.x * (256 * P1_EPB);
        int srcv[P1_EPB], dstv[P1_EPB];
        #pragma unroll
        for (int i = 0; i < P1_EPB; ++i) {
            int e = e0 + tid + (i << 8);
            bool ok = e < N_EDGES;
            srcv[i] = ok ? ei[e] : 0;
            dstv[i] = ok ? ei[N_EDGES + e] : -1;
            if (ok) atomicAdd(&hist[dstv[i] >> BUCK_SHIFT], 1);
        }
        __syncthreads();
        for (int b = tid; b < K_BUCK; b += 256) {
            int c = hist[b];
            goff[b] = c ? atomicAdd(&bucket_cnt[b], c) : 0;
            hist[b] = 0;                    // reuse as block-local cursor
        }
        __syncthreads();
        #pragma unroll
        for (int i = 0; i < P1_EPB; ++i) {
            if (dstv[i] >= 0) {
                int b = dstv[i] >> BUCK_SHIFT;
                int pos = goff[b] + atomicAdd(&hist[b], 1);
                if (pos < BUCK_CAP)         // memory-safety guard
                    part[(size_t)b * BUCK_CAP + pos] = srcv[i] | ((dstv[i] & 127) << 16);
            }
        }
        return;
    }
    int i = (blockIdx.x - P_BLOCKS) * 256 + tid;
    if (i < N_NODES * 64) {
        float2 v = x2[i];
        xb[i] = pack2(v.x, v.y);
        return;
    }
    int t = i - N_NODES * 64;
    if (t < 65536) {                        // B1[n][k], n<256, k<256
        int n = t >> 8, k = t & 255;
        float v = (k < 128) ? W1l[n * 128 + k] : W1r[n * 128 + (k - 128)];
        B1[t] = f2bf(v);
    } else if (t < 98304) {                 // B2[n][k], n<128, k<256
        int t2 = t - 65536;
        int n = t2 >> 8, k = t2 & 255;
        float v = (n < 64) ? W2l[n * 256 + k] : W2r[(n - 64) * 256 + k];
        B2[t2] = f2bf(v);
    }
}

// ---------------- build: per-bucket LDS degree/scan/cursor -> csr ----------------

__global__ __launch_bounds__(256) void build_k(const int* __restrict__ part,
                                               const int* __restrict__ bucket_cnt,
                                               int* __restrict__ rs, int* __restrict__ deg_g,
                                               float* __restrict__ inv, int* __restrict__ csr) {
    __shared__ int degl[128], rsl[128], cur[128];
    __shared__ int wred[4];
    const int b = blockIdx.x;
    const int tid = threadIdx.x, lane = tid & 63, wid = tid >> 6;
    if (tid < 128) degl[tid] = 0;
    int psum = 0;
    for (int i = tid; i < b; i += 256) psum += bucket_cnt[i];
    #pragma unroll
    for (int o = 32; o >= 1; o >>= 1) psum += __shfl_xor(psum, o);
    if (lane == 0) wred[wid] = psum;
    __syncthreads();
    const int base = wred[0] + wred[1] + wred[2] + wred[3];
    int Eb = bucket_cnt[b]; if (Eb > BUCK_CAP) Eb = BUCK_CAP;
    const int* pe = part + (size_t)b * BUCK_CAP;
    for (int i = tid; i < Eb; i += 256)
        atomicAdd(&degl[pe[i] >> 16], 1);
    __syncthreads();
    if (tid < 64) {
        int carry = 0;
        for (int c = 0; c < 128; c += 64) {
            int v = degl[c + tid];
            int sc = v;
            #pragma unroll
            for (int off = 1; off < 64; off <<= 1) {
                int t = __shfl_up(sc, off);
                if (tid >= off) sc += t;
            }
            rsl[c + tid] = carry + sc - v;
            carry += __shfl(sc, 63);
        }
    }
    __syncthreads();
    if (tid < 128) {
        int n = (b << BUCK_SHIFT) + tid;
        if (n < N_NODES) {
            int d = degl[tid];
            rs[n] = base + rsl[tid];
            deg_g[n] = d;
            inv[n] = 1.0f / fmaxf((float)d, 1.0f);
        }
        cur[tid] = 0;
    }
    __syncthreads();
    for (int i = tid; i < Eb; i += 256) {
        int e = pe[i];
        int ld = e >> 16;
        int pos = atomicAdd(&cur[ld], 1);
        csr[base + rsl[ld] + pos] = e & 0xFFFF;
    }
}

// ---------------- agg1: 2 nodes per wave, agg-half only ----------------

__global__ __launch_bounds__(256) void agg1_k(
        const int* __restrict__ rs, const int* __restrict__ deg,
        const int* __restrict__ csr, const uint* __restrict__ xb,
        const float* __restrict__ inv, uint* __restrict__ aggb) {
    const int wid = threadIdx.x >> 6, lane = threadIdx.x & 63;
    const int n0 = blockIdx.x * 8 + wid * 2;
    if (n0 >= N_NODES) return;
    const bool has1 = (n0 + 1) < N_NODES;
    const int g = lane >> 4, sub = lane & 15;
    const int beg0 = rs[n0], cnt0 = deg[n0];
    const int beg1 = has1 ? rs[n0 + 1] : 0, cnt1 = has1 ? deg[n0 + 1] : 0;
    float A0[8] = {}, A1[8] = {};
    if (cnt0 <= 64 && cnt1 <= 64) {
        int idx0 = (lane < cnt0) ? csr[beg0 + lane] : 0;
        int idx1 = (lane < cnt1) ? csr[beg1 + lane] : 0;
        int maxc = cnt0 > cnt1 ? cnt0 : cnt1;
        int nI = (maxc + 3) >> 2;
        #pragma unroll 4
        for (int i = 0; i < nI; ++i) {
            int slot = (i << 2) + g;
            int s0 = __shfl(idx0, slot);
            int s1 = __shfl(idx1, slot);
            uint4 v0 = *(const uint4*)(xb + (size_t)s0 * 64 + (sub << 2));
            uint4 v1 = *(const uint4*)(xb + (size_t)s1 * 64 + (sub << 2));
            if (slot < cnt0) ACC8(A0, v0);
            if (slot < cnt1) ACC8(A1, v1);
        }
    } else {                                 // deg>64 fallback (essentially never)
        for (int i0 = 0; i0 < cnt0; i0 += 64) {
            int rem = cnt0 - i0; if (rem > 64) rem = 64;
            int idxv = (lane < rem) ? csr[beg0 + i0 + lane] : 0;
            int nI = (rem + 3) >> 2;
            for (int i = 0; i < nI; ++i) {
                int slot = (i << 2) + g;
                int s = __shfl(idxv, slot);
                uint4 v = *(const uint4*)(xb + (size_t)s * 64 + (sub << 2));
                if (slot < rem) ACC8(A0, v);
            }
        }
        for (int i0 = 0; i0 < cnt1; i0 += 64) {
            int rem = cnt1 - i0; if (rem > 64) rem = 64;
            int idxv = (lane < rem) ? csr[beg1 + i0 + lane] : 0;
            int nI = (rem + 3) >> 2;
            for (int i = 0; i < nI; ++i) {
                int slot = (i << 2) + g;
                int s = __shfl(idxv, slot);
                uint4 v = *(const uint4*)(xb + (size_t)s * 64 + (sub << 2));
                if (slot < rem) ACC8(A1, v);
            }
        }
    }
    #pragma unroll
    for (int c = 0; c < 8; ++c) {
        A0[c] += __shfl_xor(A0[c], 16); A0[c] += __shfl_xor(A0[c], 32);
        A1[c] += __shfl_xor(A1[c], 16); A1[c] += __shfl_xor(A1[c], 32);
    }
    if (g == 0) {
        float w = inv[n0];
        uint4 o;
        o.x = pack2(A0[0] * w, A0[1] * w); o.y = pack2(A0[2] * w, A0[3] * w);
        o.z = pack2(A0[4] * w, A0[5] * w); o.w = pack2(A0[6] * w, A0[7] * w);
        *(uint4*)(aggb + (size_t)n0 * 64 + (sub << 2)) = o;
    } else if (g == 1 && has1) {
        float w = inv[n0 + 1];
        uint4 o;
        o.x = pack2(A1[0] * w, A1[1] * w); o.y = pack2(A1[2] * w, A1[3] * w);
        o.z = pack2(A1[4] * w, A1[5] * w); o.w = pack2(A1[6] * w, A1[7] * w);
        *(uint4*)(aggb + (size_t)(n0 + 1) * 64 + (sub << 2)) = o;
    }
}

// ---------------- final: 4 nodes per wave ----------------

__global__ __launch_bounds__(256) void final_k(
        const int* __restrict__ rs, const int* __restrict__ deg,
        const int* __restrict__ csr, const uint* __restrict__ t2,
        const uint* __restrict__ u2, const float* __restrict__ b2,
        const float* __restrict__ inv, float* __restrict__ out) {
    const int wid = threadIdx.x >> 6, lane = threadIdx.x & 63;
    const int base = blockIdx.x * 16 + wid * 4;
    if (base >= N_NODES) return;
    const int g = lane >> 3, sub = lane & 7;
    int begj[4], cntj[4];
    #pragma unroll
    for (int j = 0; j < 4; ++j) {
        bool ok = (base + j) < N_NODES;
        begj[j] = ok ? rs[base + j] : 0;
        cntj[j] = ok ? deg[base + j] : 0;
    }
    float A[4][8] = {};
    bool fast = cntj[0] <= 64 && cntj[1] <= 64 && cntj[2] <= 64 && cntj[3] <= 64;
    if (fast) {
        int idxr[4];
        #pragma unroll
        for (int j = 0; j < 4; ++j)
            idxr[j] = (lane < cntj[j]) ? csr[begj[j] + lane] : 0;
        int maxc = cntj[0];
        #pragma unroll
        for (int j = 1; j < 4; ++j) maxc = cntj[j] > maxc ? cntj[j] : maxc;
        int nI = (maxc + 7) >> 3;
        #pragma unroll 2
        for (int i = 0; i < nI; ++i) {
            int slot = (i << 3) + g;
            int s[4];
            #pragma unroll
            for (int j = 0; j < 4; ++j) s[j] = __shfl(idxr[j], slot);
            uint4 v[4];
            #pragma unroll
            for (int j = 0; j < 4; ++j)
                v[j] = *(const uint4*)(t2 + (size_t)s[j] * 32 + (sub << 2));
            if (slot < cntj[0]) ACC8(A[0], v[0]);
            if (slot < cntj[1]) ACC8(A[1], v[1]);
            if (slot < cntj[2]) ACC8(A[2], v[2]);
            if (slot < cntj[3]) ACC8(A[3], v[3]);
        }
    } else {
        #pragma unroll
        for (int j = 0; j < 4; ++j) {
            for (int i0 = 0; i0 < cntj[j]; i0 += 64) {
                int rem = cntj[j] - i0; if (rem > 64) rem = 64;
                int idxv = (lane < rem) ? csr[begj[j] + i0 + lane] : 0;
                int nI = (rem + 7) >> 3;
                for (int i = 0; i < nI; ++i) {
                    int slot = (i << 3) + g;
                    int s = __shfl(idxv, slot);
                    uint4 v = *(const uint4*)(t2 + (size_t)s * 32 + (sub << 2));
                    if (slot < rem) ACC8(A[j], v);
                }
            }
        }
    }
    #pragma unroll
    for (int j = 0; j < 4; ++j)
        #pragma unroll
        for (int c = 0; c < 8; ++c) {
            A[j][c] += __shfl_xor(A[j][c], 8);
            A[j][c] += __shfl_xor(A[j][c], 16);
            A[j][c] += __shfl_xor(A[j][c], 32);
        }
    #pragma unroll
    for (int j = 0; j < 4; ++j) {
        int n = base + j;
        if (g == j && n < N_NODES) {
            float w = inv[n];
            uint4 ur = *(const uint4*)(u2 + (size_t)n * 32 + (sub << 2));
            const float* br = b2 + (sub << 3);
            float4 o0, o1;
            o0.x = bflo(ur.x) + br[0] + A[j][0] * w;
            o0.y = bfhi(ur.x) + br[1] + A[j][1] * w;
            o0.z = bflo(ur.y) + br[2] + A[j][2] * w;
            o0.w = bfhi(ur.y) + br[3] + A[j][3] * w;
            o1.x = bflo(ur.z) + br[4] + A[j][4] * w;
            o1.y = bfhi(ur.z) + br[5] + A[j][5] * w;
            o1.z = bflo(ur.w) + br[6] + A[j][6] * w;
            o1.w = bfhi(ur.w) + br[7] + A[j][7] * w;
            float* orow = out + (size_t)n * 64 + (sub << 3);
            *(float4*)orow = o0;
            *(float4*)(orow + 4) = o1;
        }
    }
}

// ---------------- fused gemm12 (BK=64 panels, single-stage phase-2 B) ----------------
// grid = 391, 512 threads = 8 waves. A-tile k<128 from aggb, k>=128 from xb.
// LDS: Hs[128][136] @0 (17408), stage region S @17408: 4 panels of [128][32] (16384).
// Per half h: phase1 4 iters (stage As/Bs dual panels, 16 MFMA) -> B2half DMA issued ->
// Hs epilogue -> sync -> phase2 32 MFMAs from LDS -> sync. 20 barriers/block total.

#define HS_STRIDE 136
#define S_OFF 17408

__global__ __launch_bounds__(512) void gemm12_k(const ushort* __restrict__ aggb16,
                                                const ushort* __restrict__ xb16,
                                                const ushort* __restrict__ B1,
                                                const ushort* __restrict__ B2,
                                                const float* __restrict__ b1,
                                                ushort* __restrict__ t2,
                                                ushort* __restrict__ u2b) {
    __shared__ __align__(16) ushort lds[S_OFF + 16384];
    const int bm = blockIdx.x * 128;
    const int tid = threadIdx.x;
    const int w = tid >> 6, lane = tid & 63;
    const int q = lane >> 4, mr = lane & 15;
    const int wm = (w & 1) << 6;          // wave rows 0/64
    const int wn = (w >> 1) << 5;         // wave cols 0/32/64/96
    const int srow = tid >> 2;            // staging row 0..127
    const int scol = (tid & 3) << 3;      // ushort offset within 32-wide panel

    floatx4 acc2[4][2];
    #pragma unroll
    for (int i = 0; i < 4; ++i)
        #pragma unroll
        for (int j = 0; j < 2; ++j)
            acc2[i][j] = (floatx4){0.f, 0.f, 0.f, 0.f};

    #pragma unroll
    for (int h = 0; h < 2; ++h) {
        // ---- phase 1: acc1 = [agg|x]_tile @ B1half^T, BK=64 (2 panels/iter) ----
        floatx4 acc1[4][2];
        #pragma unroll
        for (int i = 0; i < 4; ++i)
            #pragma unroll
            for (int j = 0; j < 2; ++j)
                acc1[i][j] = (floatx4){0.f, 0.f, 0.f, 0.f};
        #pragma unroll
        for (int k0i = 0; k0i < 4; ++k0i) {
            const int k0 = k0i << 6;
            const ushort* Asrc = (k0 < 128)
                ? aggb16 + (size_t)(bm + srow) * 128 + k0
                : xb16 + (size_t)(bm + srow) * 128 + (k0 - 128);
            #pragma unroll
            for (int p = 0; p < 2; ++p) {
                gload_lds16(Asrc + (p << 5) + scol,
                            lds + S_OFF + (p << 12) + srow * 32 + scol);
                gload_lds16(B1 + (size_t)((h << 7) + srow) * 256 + k0 + (p << 5) + scol,
                            lds + S_OFF + 8192 + (p << 12) + srow * 32 + scol);
            }
            __syncthreads();
            #pragma unroll
            for (int p = 0; p < 2; ++p) {
                short8 af[4], bfr[2];
                #pragma unroll
                for (int i = 0; i < 4; ++i)
                    af[i] = *(const short8*)&lds[S_OFF + (p << 12) + (wm + (i << 4) + mr) * 32 + (q << 3)];
                #pragma unroll
                for (int j = 0; j < 2; ++j)
                    bfr[j] = *(const short8*)&lds[S_OFF + 8192 + (p << 12) + (wn + (j << 4) + mr) * 32 + (q << 3)];
                #pragma unroll
                for (int i = 0; i < 4; ++i)
                    #pragma unroll
                    for (int j = 0; j < 2; ++j)
                        acc1[i][j] = __builtin_amdgcn_mfma_f32_16x16x32_bf16(af[i], bfr[j], acc1[i][j], 0, 0, 0);
            }
            __syncthreads();
        }
        // ---- issue phase-2 B staging now (overlaps epilogue below) ----
        #pragma unroll
        for (int p = 0; p < 4; ++p)
            gload_lds16(B2 + (size_t)srow * 256 + (h << 7) + (p << 5) + scol,
                        lds + S_OFF + (p << 12) + srow * 32 + scol);
        // ---- epilogue 1: relu+bias -> Hs (bf16) ----
        #pragma unroll
        for (int i = 0; i < 4; ++i) {
            int row = wm + (i << 4) + (q << 2);
            #pragma unroll
            for (int j = 0; j < 2; ++j) {
                int col = wn + (j << 4) + mr;
                float bv = b1[(h << 7) + col];
                #pragma unroll
                for (int r = 0; r < 4; ++r) {
                    float v = fmaxf(acc1[i][j][r] + bv, 0.f);
                    lds[(row + r) * HS_STRIDE + col] = f2bf(v);
                }
            }
        }
        __syncthreads();
        // ---- phase 2: acc2 += Hs @ B2half^T, all from LDS, no staging barriers ----
        #pragma unroll
        for (int p = 0; p < 4; ++p) {
            short8 af2[4], bf2[2];
            #pragma unroll
            for (int i = 0; i < 4; ++i)
                af2[i] = *(const short8*)&lds[(wm + (i << 4) + mr) * HS_STRIDE + (p << 5) + (q << 3)];
            #pragma unroll
            for (int j = 0; j < 2; ++j)
                bf2[j] = *(const short8*)&lds[S_OFF + (p << 12) + (wn + (j << 4) + mr) * 32 + (q << 3)];
            #pragma unroll
            for (int i = 0; i < 4; ++i)
                #pragma unroll
                for (int j = 0; j < 2; ++j)
                    acc2[i][j] = __builtin_amdgcn_mfma_f32_16x16x32_bf16(af2[i], bf2[j], acc2[i][j], 0, 0, 0);
        }
        __syncthreads();
    }
    // ---- epilogue 2: t2 (cols 0..63, bf16) | u2 (cols 64..127, bf16) ----
    #pragma unroll
    for (int i = 0; i < 4; ++i) {
        int row = bm + wm + (i << 4) + (q << 2);
        #pragma unroll
        for (int j = 0; j < 2; ++j) {
            int col = wn + (j << 4) + mr;
            #pragma unroll
            for (int r = 0; r < 4; ++r) {
                float v = acc2[i][j][r];
                if (col < 64) t2[(size_t)(row + r) * 64 + col] = f2bf(v);
                else          u2b[(size_t)(row + r) * 64 + (col - 64)] = f2bf(v);
            }
        }
    }
}

// ---------------- launch ----------------

extern "C" void kernel_launch(void* const* d_in, const int* in_sizes, int n_in,
                              void* d_out, int out_size, void* d_ws, size_t ws_size,
                              hipStream_t stream) {
    const float* x   = (const float*)d_in[0];
    const int*   ei  = (const int*)d_in[1];
    const float* W1l = (const float*)d_in[2];
    const float* W1r = (const float*)d_in[3];
    const float* b1  = (const float*)d_in[4];
    const float* W2l = (const float*)d_in[5];
    const float* W2r = (const float*)d_in[6];
    const float* b2  = (const float*)d_in[7];
    float* out = (float*)d_out;

    char* base = (char*)d_ws;
    size_t off = 0;
    auto alloc = [&](size_t bytes) -> void* {
        void* p = base + off;
        off = (off + bytes + 255) & ~(size_t)255;
        return p;
    };
    int*    deg        = (int*)alloc(M_PAD * 4);
    int*    rs         = (int*)alloc(M_PAD * 4);
    float*  inv        = (float*)alloc(M_PAD * 4);
    int*    bucket_cnt = (int*)alloc(K_BUCK * 4);
    int*    csr        = (int*)alloc((size_t)N_EDGES * 4);
    int*    part       = (int*)alloc((size_t)K_BUCK * BUCK_CAP * 4);
    uint*   xb         = (uint*)alloc((size_t)M_PAD * 64 * 4);   // padded to M_PAD rows
    uint*   aggb       = (uint*)alloc((size_t)M_PAD * 64 * 4);   // bf16 [M_PAD][128]
    uint*   t2         = (uint*)alloc((size_t)M_PAD * 32 * 4);
    uint*   u2         = (uint*)alloc((size_t)M_PAD * 32 * 4);
    ushort* B1         = (ushort*)alloc(256 * 256 * 2);
    ushort* B2         = (ushort*)alloc(128 * 256 * 2);

    hipMemsetAsync(bucket_cnt, 0, K_BUCK * sizeof(int), stream);

    entry_k<<<P_BLOCKS + PREP_ELEMS / 256, 256, 0, stream>>>(
        ei, bucket_cnt, part, (const float2*)x, xb, W1l, W1r, W2l, W2r, B1, B2);

    build_k<<<K_BUCK, 256, 0, stream>>>(part, bucket_cnt, rs, deg, inv, csr);

    agg1_k<<<(N_NODES + 7) / 8, 256, 0, stream>>>(rs, deg, csr, xb, inv, aggb);

    gemm12_k<<<K_BUCK, 512, 0, stream>>>((const ushort*)aggb, (const ushort*)xb,
                                         B1, B2, b1, (ushort*)t2, (ushort*)u2);

    final_k<<<(N_NODES + 15) / 16, 256, 0, stream>>>(rs, deg, csr, t2, u2, b2, inv, out);
}

// Round 8
// 171.064 us; speedup vs baseline: 2.9566x; 1.0735x over previous
//
#include <hip/hip_runtime.h>
#include <hip/hip_bf16.h>

// GraphSAGE 2-layer forward, bf16-MFMA inner pipeline.
// R8: group-per-node zero-shuffle gathers. csr is ushort (src<65536), per-node
//     segments padded to x4 inside fixed 4608-entry bucket regions (no global
//     prefix sums). buildagg_k = build + agg1 fused, bucket csr kept in LDS;
//     idx arrives via broadcast 8B loads; no cross-lane reduction trees.
// Dispatches: memset(1.5KB) -> entry -> buildagg -> gemm12 -> final.

#define N_NODES 50000
#define N_EDGES 800000
#define M_PAD   50048   // 391 * 128

#define BUCK_SHIFT 7
#define K_BUCK 391            // ceil(50000/128)
#define BUCK_CAP 4096         // bucket edges: mean 2046, sigma ~45 (guarded anyway)
#define CSR_SEG 4608          // fixed per-bucket csr region (>= BUCK_CAP + 128*3 pad)
#define P1_EPB 16             // edges per thread in partition phase (4096/block)
#define P_BLOCKS 196          // ceil(800000/4096)
#define PREP_ELEMS (N_NODES * 64 + 98304)   // 3298304 = 12884*256 exactly

typedef unsigned int uint;
typedef unsigned short ushort;
typedef __attribute__((ext_vector_type(8))) short short8;
typedef __attribute__((ext_vector_type(4))) float floatx4;

__device__ __forceinline__ ushort f2bf(float f) {
    union { float f; uint u; } c; c.f = f;
    uint u = c.u;
    return (ushort)((u + 0x7FFFu + ((u >> 16) & 1u)) >> 16);  // RNE
}
__device__ __forceinline__ uint pack2(float lo, float hi) {
    return (uint)f2bf(lo) | ((uint)f2bf(hi) << 16);
}
__device__ __forceinline__ float bflo(uint v) { return __uint_as_float(v << 16); }
__device__ __forceinline__ float bfhi(uint v) { return __uint_as_float(v & 0xffff0000u); }
__device__ __forceinline__ void gload_lds16(const ushort* g, ushort* l) {
    __builtin_amdgcn_global_load_lds(
        (const __attribute__((address_space(1))) void*)g,
        (__attribute__((address_space(3))) void*)l, 16, 0, 0);
}

#define ACC8(A, v) { A[0] += bflo(v.x); A[1] += bfhi(v.x); A[2] += bflo(v.y); A[3] += bfhi(v.y); \
                     A[4] += bflo(v.z); A[5] += bfhi(v.z); A[6] += bflo(v.w); A[7] += bfhi(v.w); }

// ---------------- entry: partition (blocks < P_BLOCKS) + dtype prep ----------------

__global__ __launch_bounds__(256) void entry_k(
        const int* __restrict__ ei, int* __restrict__ bucket_cnt, int* __restrict__ part,
        const float2* __restrict__ x2, uint* __restrict__ xb,
        const float* __restrict__ W1l, const float* __restrict__ W1r,
        const float* __restrict__ W2l, const float* __restrict__ W2r,
        ushort* __restrict__ B1, ushort* __restrict__ B2) {
    __shared__ int hist[K_BUCK];
    __shared__ int goff[K_BUCK];
    const int tid = threadIdx.x;
    if (blockIdx.x < P_BLOCKS) {
        for (int i = tid; i < K_BUCK; i += 256) hist[i] = 0;
        __syncthreads();
        const int e0 = blockIdx.x * (256 * P1_EPB);
        int srcv[P1_EPB], dstv[P1_EPB];
        #pragma unroll
        for (int i = 0; i < P1_EPB; ++i) {
            int e = e0 + tid + (i << 8);
            bool ok = e < N_EDGES;
            srcv[i] = ok ? ei[e] : 0;
            dstv[i] = ok ? ei[N_EDGES + e] : -1;
            if (ok) atomicAdd(&hist[dstv[i] >> BUCK_SHIFT], 1);
        }
        __syncthreads();
        for (int b = tid; b < K_BUCK; b += 256) {
            int c = hist[b];
            goff[b] = c ? atomicAdd(&bucket_cnt[b], c) : 0;
            hist[b] = 0;                    // reuse as block-local cursor
        }
        __syncthreads();
        #pragma unroll
        for (int i = 0; i < P1_EPB; ++i) {
            if (dstv[i] >= 0) {
                int b = dstv[i] >> BUCK_SHIFT;
                int pos = goff[b] + atomicAdd(&hist[b], 1);
                if (pos < BUCK_CAP)         // memory-safety guard
                    part[(size_t)b * BUCK_CAP + pos] = srcv[i] | ((dstv[i] & 127) << 16);
            }
        }
        return;
    }
    int i = (blockIdx.x - P_BLOCKS) * 256 + tid;
    if (i < N_NODES * 64) {
        float2 v = x2[i];
        xb[i] = pack2(v.x, v.y);
        return;
    }
    int t = i - N_NODES * 64;
    if (t < 65536) {                        // B1[n][k], n<256, k<256
        int n = t >> 8, k = t & 255;
        float v = (k < 128) ? W1l[n * 128 + k] : W1r[n * 128 + (k - 128)];
        B1[t] = f2bf(v);
    } else if (t < 98304) {                 // B2[n][k], n<128, k<256
        int t2 = t - 65536;
        int n = t2 >> 8, k = t2 & 255;
        float v = (n < 64) ? W2l[n * 256 + k] : W2r[(n - 64) * 256 + k];
        B2[t2] = f2bf(v);
    }
}

// ---------------- buildagg: CSR build (LDS-resident) + layer-1 mean-gather ----------------
// 391 blocks x 512 threads. Build: degree hist -> padded scan -> LDS csr (+global copy).
// Agg: 32 groups x 16 lanes, 4 nodes/group; per round a broadcast ds_read_b64 gives
// 4 src ids -> 4 independent uint4 row gathers -> masked fp32 accumulate.

__global__ __launch_bounds__(512) void buildagg_k(
        const int* __restrict__ part, const int* __restrict__ bucket_cnt,
        int* __restrict__ rs, int* __restrict__ deg_g, float* __restrict__ inv,
        ushort* __restrict__ csr16, const uint* __restrict__ xb,
        uint* __restrict__ aggb) {
    __shared__ int degl[128], rsl[128], cur[128];
    __shared__ ushort csr_l[CSR_SEG];
    const int b = blockIdx.x;
    const int tid = threadIdx.x;
    if (tid < 128) { degl[tid] = 0; cur[tid] = 0; }
    for (int i = tid; i < CSR_SEG; i += 512) csr_l[i] = 0;
    int Eb = bucket_cnt[b]; if (Eb > BUCK_CAP) Eb = BUCK_CAP;
    const int* pe = part + (size_t)b * BUCK_CAP;
    __syncthreads();
    for (int i = tid; i < Eb; i += 512)
        atomicAdd(&degl[pe[i] >> 16], 1);
    __syncthreads();
    if (tid < 64) {                          // wave 0: exclusive scan of x4-padded degs
        int carry = 0;
        for (int c = 0; c < 128; c += 64) {
            int v = (degl[c + tid] + 3) & ~3;
            int sc = v;
            #pragma unroll
            for (int off = 1; off < 64; off <<= 1) {
                int t = __shfl_up(sc, off);
                if (tid >= off) sc += t;
            }
            rsl[c + tid] = carry + sc - v;
            carry += __shfl(sc, 63);
        }
    }
    __syncthreads();
    if (tid < 128) {
        int n = (b << BUCK_SHIFT) + tid;
        if (n < N_NODES) {
            rs[n] = b * CSR_SEG + rsl[tid];
            deg_g[n] = degl[tid];
            inv[n] = 1.0f / fmaxf((float)degl[tid], 1.0f);
        }
    }
    __syncthreads();
    for (int i = tid; i < Eb; i += 512) {
        int e = pe[i];
        int ld = e >> 16;
        int pos = atomicAdd(&cur[ld], 1);
        int o = rsl[ld] + pos;
        ushort s = (ushort)(e & 0xFFFF);
        csr_l[o] = s;
        csr16[(size_t)b * CSR_SEG + o] = s;
    }
    __syncthreads();
    // ---- agg phase ----
    const int g = tid >> 4, sub = tid & 15;
    #pragma unroll
    for (int v = 0; v < 4; ++v) {
        const int ln = g * 4 + v;
        const int n = (b << BUCK_SHIFT) + ln;
        if (n >= N_NODES) continue;
        const int beg = rsl[ln], cnt = degl[ln];
        float A[8] = {};
        const int nR = (cnt + 3) >> 2;
        #pragma unroll 4
        for (int r = 0; r < nR; ++r) {
            uint2 i2 = *(const uint2*)&csr_l[beg + (r << 2)];   // 4 src ids, broadcast
            int s0 = i2.x & 0xFFFF, s1 = i2.x >> 16;
            int s2 = i2.y & 0xFFFF, s3 = i2.y >> 16;
            uint4 v0 = *(const uint4*)(xb + (size_t)s0 * 64 + (sub << 2));
            uint4 v1 = *(const uint4*)(xb + (size_t)s1 * 64 + (sub << 2));
            uint4 v2 = *(const uint4*)(xb + (size_t)s2 * 64 + (sub << 2));
            uint4 v3 = *(const uint4*)(xb + (size_t)s3 * 64 + (sub << 2));
            int e0 = r << 2;
            if (e0 + 0 < cnt) ACC8(A, v0);
            if (e0 + 1 < cnt) ACC8(A, v1);
            if (e0 + 2 < cnt) ACC8(A, v2);
            if (e0 + 3 < cnt) ACC8(A, v3);
        }
        const float w = 1.0f / fmaxf((float)cnt, 1.0f);
        uint4 o;
        o.x = pack2(A[0] * w, A[1] * w); o.y = pack2(A[2] * w, A[3] * w);
        o.z = pack2(A[4] * w, A[5] * w); o.w = pack2(A[6] * w, A[7] * w);
        *(uint4*)(aggb + (size_t)n * 64 + (sub << 2)) = o;
    }
}

// ---------------- final: group-per-node (8 lanes), broadcast idx, no reduce ----------------

__global__ __launch_bounds__(256) void final_k(
        const int* __restrict__ rs, const int* __restrict__ deg,
        const ushort* __restrict__ csr16, const uint* __restrict__ t2,
        const uint* __restrict__ u2, const float* __restrict__ b2,
        const float* __restrict__ inv, float* __restrict__ out) {
    const int tid = threadIdx.x, lane = tid & 63, wid = tid >> 6;
    const int g = lane >> 3, sub = lane & 7;
    const int n = blockIdx.x * 32 + wid * 8 + g;
    if (n >= N_NODES) return;
    const int beg = rs[n], cnt = deg[n];
    float A[8] = {};
    const int nR = (cnt + 3) >> 2;
    #pragma unroll 4
    for (int r = 0; r < nR; ++r) {
        uint2 i2 = *(const uint2*)(csr16 + beg + (r << 2));     // 4 src ids, broadcast
        int s0 = i2.x & 0xFFFF, s1 = i2.x >> 16;
        int s2 = i2.y & 0xFFFF, s3 = i2.y >> 16;
        uint4 v0 = *(const uint4*)(t2 + (size_t)s0 * 32 + (sub << 2));
        uint4 v1 = *(const uint4*)(t2 + (size_t)s1 * 32 + (sub << 2));
        uint4 v2 = *(const uint4*)(t2 + (size_t)s2 * 32 + (sub << 2));
        uint4 v3 = *(const uint4*)(t2 + (size_t)s3 * 32 + (sub << 2));
        int e0 = r << 2;
        if (e0 + 0 < cnt) ACC8(A, v0);
        if (e0 + 1 < cnt) ACC8(A, v1);
        if (e0 + 2 < cnt) ACC8(A, v2);
        if (e0 + 3 < cnt) ACC8(A, v3);
    }
    const float w = inv[n];
    uint4 ur = *(const uint4*)(u2 + (size_t)n * 32 + (sub << 2));
    const float* br = b2 + (sub << 3);
    float4 o0, o1;
    o0.x = bflo(ur.x) + br[0] + A[0] * w;
    o0.y = bfhi(ur.x) + br[1] + A[1] * w;
    o0.z = bflo(ur.y) + br[2] + A[2] * w;
    o0.w = bfhi(ur.y) + br[3] + A[3] * w;
    o1.x = bflo(ur.z) + br[4] + A[4] * w;
    o1.y = bfhi(ur.z) + br[5] + A[5] * w;
    o1.z = bflo(ur.w) + br[6] + A[6] * w;
    o1.w = bfhi(ur.w) + br[7] + A[7] * w;
    float* orow = out + (size_t)n * 64 + (sub << 3);
    *(float4*)orow = o0;
    *(float4*)(orow + 4) = o1;
}

// ---------------- fused gemm12 (BK=64 panels, single-stage phase-2 B) ----------------
// grid = 391, 512 threads = 8 waves. A-tile k<128 from aggb, k>=128 from xb.
// LDS: Hs[128][136] @0 (17408), stage region S @17408: 4 panels of [128][32].
// 20 barriers/block; B2 DMA overlaps Hs epilogue.

#define HS_STRIDE 136
#define S_OFF 17408

__global__ __launch_bounds__(512) void gemm12_k(const ushort* __restrict__ aggb16,
                                                const ushort* __restrict__ xb16,
                                                const ushort* __restrict__ B1,
                                                const ushort* __restrict__ B2,
                                                const float* __restrict__ b1,
                                                ushort* __restrict__ t2,
                                                ushort* __restrict__ u2b) {
    __shared__ __align__(16) ushort lds[S_OFF + 16384];
    const int bm = blockIdx.x * 128;
    const int tid = threadIdx.x;
    const int w = tid >> 6, lane = tid & 63;
    const int q = lane >> 4, mr = lane & 15;
    const int wm = (w & 1) << 6;          // wave rows 0/64
    const int wn = (w >> 1) << 5;         // wave cols 0/32/64/96
    const int srow = tid >> 2;            // staging row 0..127
    const int scol = (tid & 3) << 3;      // ushort offset within 32-wide panel

    floatx4 acc2[4][2];
    #pragma unroll
    for (int i = 0; i < 4; ++i)
        #pragma unroll
        for (int j = 0; j < 2; ++j)
            acc2[i][j] = (floatx4){0.f, 0.f, 0.f, 0.f};

    #pragma unroll
    for (int h = 0; h < 2; ++h) {
        floatx4 acc1[4][2];
        #pragma unroll
        for (int i = 0; i < 4; ++i)
            #pragma unroll
            for (int j = 0; j < 2; ++j)
                acc1[i][j] = (floatx4){0.f, 0.f, 0.f, 0.f};
        #pragma unroll
        for (int k0i = 0; k0i < 4; ++k0i) {
            const int k0 = k0i << 6;
            const ushort* Asrc = (k0 < 128)
                ? aggb16 + (size_t)(bm + srow) * 128 + k0
                : xb16 + (size_t)(bm + srow) * 128 + (k0 - 128);
            #pragma unroll
            for (int p = 0; p < 2; ++p) {
                gload_lds16(Asrc + (p << 5) + scol,
                            lds + S_OFF + (p << 12) + srow * 32 + scol);
                gload_lds16(B1 + (size_t)((h << 7) + srow) * 256 + k0 + (p << 5) + scol,
                            lds + S_OFF + 8192 + (p << 12) + srow * 32 + scol);
            }
            __syncthreads();
            #pragma unroll
            for (int p = 0; p < 2; ++p) {
                short8 af[4], bfr[2];
                #pragma unroll
                for (int i = 0; i < 4; ++i)
                    af[i] = *(const short8*)&lds[S_OFF + (p << 12) + (wm + (i << 4) + mr) * 32 + (q << 3)];
                #pragma unroll
                for (int j = 0; j < 2; ++j)
                    bfr[j] = *(const short8*)&lds[S_OFF + 8192 + (p << 12) + (wn + (j << 4) + mr) * 32 + (q << 3)];
                #pragma unroll
                for (int i = 0; i < 4; ++i)
                    #pragma unroll
                    for (int j = 0; j < 2; ++j)
                        acc1[i][j] = __builtin_amdgcn_mfma_f32_16x16x32_bf16(af[i], bfr[j], acc1[i][j], 0, 0, 0);
            }
            __syncthreads();
        }
        #pragma unroll
        for (int p = 0; p < 4; ++p)
            gload_lds16(B2 + (size_t)srow * 256 + (h << 7) + (p << 5) + scol,
                        lds + S_OFF + (p << 12) + srow * 32 + scol);
        #pragma unroll
        for (int i = 0; i < 4; ++i) {
            int row = wm + (i << 4) + (q << 2);
            #pragma unroll
            for (int j = 0; j < 2; ++j) {
                int col = wn + (j << 4) + mr;
                float bv = b1[(h << 7) + col];
                #pragma unroll
                for (int r = 0; r < 4; ++r) {
                    float v = fmaxf(acc1[i][j][r] + bv, 0.f);
                    lds[(row + r) * HS_STRIDE + col] = f2bf(v);
                }
            }
        }
        __syncthreads();
        #pragma unroll
        for (int p = 0; p < 4; ++p) {
            short8 af2[4], bf2[2];
            #pragma unroll
            for (int i = 0; i < 4; ++i)
                af2[i] = *(const short8*)&lds[(wm + (i << 4) + mr) * HS_STRIDE + (p << 5) + (q << 3)];
            #pragma unroll
            for (int j = 0; j < 2; ++j)
                bf2[j] = *(const short8*)&lds[S_OFF + (p << 12) + (wn + (j << 4) + mr) * 32 + (q << 3)];
            #pragma unroll
            for (int i = 0; i < 4; ++i)
                #pragma unroll
                for (int j = 0; j < 2; ++j)
                    acc2[i][j] = __builtin_amdgcn_mfma_f32_16x16x32_bf16(af2[i], bf2[j], acc2[i][j], 0, 0, 0);
        }
        __syncthreads();
    }
    #pragma unroll
    for (int i = 0; i < 4; ++i) {
        int row = bm + wm + (i << 4) + (q << 2);
        #pragma unroll
        for (int j = 0; j < 2; ++j) {
            int col = wn + (j << 4) + mr;
            #pragma unroll
            for (int r = 0; r < 4; ++r) {
                float v = acc2[i][j][r];
                if (col < 64) t2[(size_t)(row + r) * 64 + col] = f2bf(v);
                else          u2b[(size_t)(row + r) * 64 + (col - 64)] = f2bf(v);
            }
        }
    }
}

// ---------------- launch ----------------

extern "C" void kernel_launch(void* const* d_in, const int* in_sizes, int n_in,
                              void* d_out, int out_size, void* d_ws, size_t ws_size,
                              hipStream_t stream) {
    const float* x   = (const float*)d_in[0];
    const int*   ei  = (const int*)d_in[1];
    const float* W1l = (const float*)d_in[2];
    const float* W1r = (const float*)d_in[3];
    const float* b1  = (const float*)d_in[4];
    const float* W2l = (const float*)d_in[5];
    const float* W2r = (const float*)d_in[6];
    const float* b2  = (const float*)d_in[7];
    float* out = (float*)d_out;

    char* base = (char*)d_ws;
    size_t off = 0;
    auto alloc = [&](size_t bytes) -> void* {
        void* p = base + off;
        off = (off + bytes + 255) & ~(size_t)255;
        return p;
    };
    int*    deg        = (int*)alloc(M_PAD * 4);
    int*    rs         = (int*)alloc(M_PAD * 4);
    float*  inv        = (float*)alloc(M_PAD * 4);
    int*    bucket_cnt = (int*)alloc(K_BUCK * 4);
    ushort* csr16      = (ushort*)alloc((size_t)K_BUCK * CSR_SEG * 2);
    int*    part       = (int*)alloc((size_t)K_BUCK * BUCK_CAP * 4);
    uint*   xb         = (uint*)alloc((size_t)M_PAD * 64 * 4);   // bf16 [M_PAD][128]
    uint*   aggb       = (uint*)alloc((size_t)M_PAD * 64 * 4);   // bf16 [M_PAD][128]
    uint*   t2         = (uint*)alloc((size_t)M_PAD * 32 * 4);
    uint*   u2         = (uint*)alloc((size_t)M_PAD * 32 * 4);
    ushort* B1         = (ushort*)alloc(256 * 256 * 2);
    ushort* B2         = (ushort*)alloc(128 * 256 * 2);

    hipMemsetAsync(bucket_cnt, 0, K_BUCK * sizeof(int), stream);

    entry_k<<<P_BLOCKS + PREP_ELEMS / 256, 256, 0, stream>>>(
        ei, bucket_cnt, part, (const float2*)x, xb, W1l, W1r, W2l, W2r, B1, B2);

    buildagg_k<<<K_BUCK, 512, 0, stream>>>(part, bucket_cnt, rs, deg, inv,
                                           csr16, xb, aggb);

    gemm12_k<<<K_BUCK, 512, 0, stream>>>((const ushort*)aggb, (const ushort*)xb,
                                         B1, B2, b1, (ushort*)t2, (ushort*)u2);

    final_k<<<(N_NODES + 31) / 32, 256, 0, stream>>>(rs, deg, csr16, t2, u2, b2, inv, out);
}

// Round 9
// 170.078 us; speedup vs baseline: 2.9737x; 1.0058x over previous
//
#include <hip/hip_runtime.h>
#include <hip/hip_bf16.h>

// GraphSAGE 2-layer forward, bf16-MFMA inner pipeline.
// R9: buildagg agg-phase processes node PAIRS (8 gather loads in flight per
//     16-lane group, 2x MLP); gemm12 phase-1 uses ping-pong double-buffered
//     staging (DMA overlaps MFMA instead of barrier-draining cold).
// Dispatches: memset(1.5KB) -> entry -> buildagg -> gemm12 -> final.

#define N_NODES 50000
#define N_EDGES 800000
#define M_PAD   50048   // 391 * 128

#define BUCK_SHIFT 7
#define K_BUCK 391            // ceil(50000/128)
#define BUCK_CAP 4096         // bucket edges: mean 2046, sigma ~45 (guarded anyway)
#define CSR_SEG 4608          // fixed per-bucket csr region (>= BUCK_CAP + 128*3 pad)
#define P1_EPB 16             // edges per thread in partition phase (4096/block)
#define P_BLOCKS 196          // ceil(800000/4096)
#define PREP_ELEMS (N_NODES * 64 + 98304)   // 3298304 = 12884*256 exactly

typedef unsigned int uint;
typedef unsigned short ushort;
typedef __attribute__((ext_vector_type(8))) short short8;
typedef __attribute__((ext_vector_type(4))) float floatx4;

__device__ __forceinline__ ushort f2bf(float f) {
    union { float f; uint u; } c; c.f = f;
    uint u = c.u;
    return (ushort)((u + 0x7FFFu + ((u >> 16) & 1u)) >> 16);  // RNE
}
__device__ __forceinline__ uint pack2(float lo, float hi) {
    return (uint)f2bf(lo) | ((uint)f2bf(hi) << 16);
}
__device__ __forceinline__ float bflo(uint v) { return __uint_as_float(v << 16); }
__device__ __forceinline__ float bfhi(uint v) { return __uint_as_float(v & 0xffff0000u); }
__device__ __forceinline__ void gload_lds16(const ushort* g, ushort* l) {
    __builtin_amdgcn_global_load_lds(
        (const __attribute__((address_space(1))) void*)g,
        (__attribute__((address_space(3))) void*)l, 16, 0, 0);
}

#define ACC8(A, v) { A[0] += bflo(v.x); A[1] += bfhi(v.x); A[2] += bflo(v.y); A[3] += bfhi(v.y); \
                     A[4] += bflo(v.z); A[5] += bfhi(v.z); A[6] += bflo(v.w); A[7] += bfhi(v.w); }

// ---------------- entry: partition (blocks < P_BLOCKS) + dtype prep ----------------

__global__ __launch_bounds__(256) void entry_k(
        const int* __restrict__ ei, int* __restrict__ bucket_cnt, int* __restrict__ part,
        const float2* __restrict__ x2, uint* __restrict__ xb,
        const float* __restrict__ W1l, const float* __restrict__ W1r,
        const float* __restrict__ W2l, const float* __restrict__ W2r,
        ushort* __restrict__ B1, ushort* __restrict__ B2) {
    __shared__ int hist[K_BUCK];
    __shared__ int goff[K_BUCK];
    const int tid = threadIdx.x;
    if (blockIdx.x < P_BLOCKS) {
        for (int i = tid; i < K_BUCK; i += 256) hist[i] = 0;
        __syncthreads();
        const int e0 = blockIdx.x * (256 * P1_EPB);
        int srcv[P1_EPB], dstv[P1_EPB];
        #pragma unroll
        for (int i = 0; i < P1_EPB; ++i) {
            int e = e0 + tid + (i << 8);
            bool ok = e < N_EDGES;
            srcv[i] = ok ? ei[e] : 0;
            dstv[i] = ok ? ei[N_EDGES + e] : -1;
            if (ok) atomicAdd(&hist[dstv[i] >> BUCK_SHIFT], 1);
        }
        __syncthreads();
        for (int b = tid; b < K_BUCK; b += 256) {
            int c = hist[b];
            goff[b] = c ? atomicAdd(&bucket_cnt[b], c) : 0;
            hist[b] = 0;                    // reuse as block-local cursor
        }
        __syncthreads();
        #pragma unroll
        for (int i = 0; i < P1_EPB; ++i) {
            if (dstv[i] >= 0) {
                int b = dstv[i] >> BUCK_SHIFT;
                int pos = goff[b] + atomicAdd(&hist[b], 1);
                if (pos < BUCK_CAP)         // memory-safety guard
                    part[(size_t)b * BUCK_CAP + pos] = srcv[i] | ((dstv[i] & 127) << 16);
            }
        }
        return;
    }
    int i = (blockIdx.x - P_BLOCKS) * 256 + tid;
    if (i < N_NODES * 64) {
        float2 v = x2[i];
        xb[i] = pack2(v.x, v.y);
        return;
    }
    int t = i - N_NODES * 64;
    if (t < 65536) {                        // B1[n][k], n<256, k<256
        int n = t >> 8, k = t & 255;
        float v = (k < 128) ? W1l[n * 128 + k] : W1r[n * 128 + (k - 128)];
        B1[t] = f2bf(v);
    } else if (t < 98304) {                 // B2[n][k], n<128, k<256
        int t2 = t - 65536;
        int n = t2 >> 8, k = t2 & 255;
        float v = (n < 64) ? W2l[n * 256 + k] : W2r[(n - 64) * 256 + k];
        B2[t2] = f2bf(v);
    }
}

// ---------------- buildagg: CSR build (LDS-resident) + layer-1 mean-gather ----------------
// 391 blocks x 512 threads. Agg: 32 groups x 16 lanes, node PAIRS interleaved:
// per round one broadcast 8B idx load per node -> 8 independent uint4 gathers.

__global__ __launch_bounds__(512) void buildagg_k(
        const int* __restrict__ part, const int* __restrict__ bucket_cnt,
        int* __restrict__ rs, int* __restrict__ deg_g, float* __restrict__ inv,
        ushort* __restrict__ csr16, const uint* __restrict__ xb,
        uint* __restrict__ aggb) {
    __shared__ int degl[128], rsl[128], cur[128];
    __shared__ ushort csr_l[CSR_SEG];
    const int b = blockIdx.x;
    const int tid = threadIdx.x;
    if (tid < 128) { degl[tid] = 0; cur[tid] = 0; }
    for (int i = tid; i < CSR_SEG; i += 512) csr_l[i] = 0;
    int Eb = bucket_cnt[b]; if (Eb > BUCK_CAP) Eb = BUCK_CAP;
    const int* pe = part + (size_t)b * BUCK_CAP;
    __syncthreads();
    for (int i = tid; i < Eb; i += 512)
        atomicAdd(&degl[pe[i] >> 16], 1);
    __syncthreads();
    if (tid < 64) {                          // wave 0: exclusive scan of x4-padded degs
        int carry = 0;
        for (int c = 0; c < 128; c += 64) {
            int v = (degl[c + tid] + 3) & ~3;
            int sc = v;
            #pragma unroll
            for (int off = 1; off < 64; off <<= 1) {
                int t = __shfl_up(sc, off);
                if (tid >= off) sc += t;
            }
            rsl[c + tid] = carry + sc - v;
            carry += __shfl(sc, 63);
        }
    }
    __syncthreads();
    if (tid < 128) {
        int n = (b << BUCK_SHIFT) + tid;
        if (n < N_NODES) {
            rs[n] = b * CSR_SEG + rsl[tid];
            deg_g[n] = degl[tid];
            inv[n] = 1.0f / fmaxf((float)degl[tid], 1.0f);
        }
    }
    __syncthreads();
    for (int i = tid; i < Eb; i += 512) {
        int e = pe[i];
        int ld = e >> 16;
        int pos = atomicAdd(&cur[ld], 1);
        int o = rsl[ld] + pos;
        ushort s = (ushort)(e & 0xFFFF);
        csr_l[o] = s;
        csr16[(size_t)b * CSR_SEG + o] = s;
    }
    __syncthreads();
    // ---- agg phase: node pairs ----
    const int g = tid >> 4, sub = tid & 15;
    #pragma unroll
    for (int v = 0; v < 4; v += 2) {
        const int ln0 = g * 4 + v, ln1 = ln0 + 1;
        const int n0 = (b << BUCK_SHIFT) + ln0, n1 = n0 + 1;
        if (n0 >= N_NODES) continue;
        const int beg0 = rsl[ln0], cnt0 = degl[ln0];
        const int beg1 = rsl[ln1], cnt1 = (n1 < N_NODES) ? degl[ln1] : 0;
        float A0[8] = {}, A1[8] = {};
        const int maxc = cnt0 > cnt1 ? cnt0 : cnt1;
        const int nR = (maxc + 3) >> 2;
        #pragma unroll 2
        for (int r = 0; r < nR; ++r) {
            uint2 i0 = *(const uint2*)&csr_l[beg0 + (r << 2)];
            uint2 i1 = *(const uint2*)&csr_l[beg1 + (r << 2)];
            uint4 v00 = *(const uint4*)(xb + (size_t)(i0.x & 0xFFFF) * 64 + (sub << 2));
            uint4 v01 = *(const uint4*)(xb + (size_t)(i0.x >> 16)    * 64 + (sub << 2));
            uint4 v02 = *(const uint4*)(xb + (size_t)(i0.y & 0xFFFF) * 64 + (sub << 2));
            uint4 v03 = *(const uint4*)(xb + (size_t)(i0.y >> 16)    * 64 + (sub << 2));
            uint4 v10 = *(const uint4*)(xb + (size_t)(i1.x & 0xFFFF) * 64 + (sub << 2));
            uint4 v11 = *(const uint4*)(xb + (size_t)(i1.x >> 16)    * 64 + (sub << 2));
            uint4 v12 = *(const uint4*)(xb + (size_t)(i1.y & 0xFFFF) * 64 + (sub << 2));
            uint4 v13 = *(const uint4*)(xb + (size_t)(i1.y >> 16)    * 64 + (sub << 2));
            int e0 = r << 2;
            if (e0 + 0 < cnt0) ACC8(A0, v00);
            if (e0 + 1 < cnt0) ACC8(A0, v01);
            if (e0 + 2 < cnt0) ACC8(A0, v02);
            if (e0 + 3 < cnt0) ACC8(A0, v03);
            if (e0 + 0 < cnt1) ACC8(A1, v10);
            if (e0 + 1 < cnt1) ACC8(A1, v11);
            if (e0 + 2 < cnt1) ACC8(A1, v12);
            if (e0 + 3 < cnt1) ACC8(A1, v13);
        }
        {
            const float w = 1.0f / fmaxf((float)cnt0, 1.0f);
            uint4 o;
            o.x = pack2(A0[0] * w, A0[1] * w); o.y = pack2(A0[2] * w, A0[3] * w);
            o.z = pack2(A0[4] * w, A0[5] * w); o.w = pack2(A0[6] * w, A0[7] * w);
            *(uint4*)(aggb + (size_t)n0 * 64 + (sub << 2)) = o;
        }
        if (n1 < N_NODES) {
            const float w = 1.0f / fmaxf((float)cnt1, 1.0f);
            uint4 o;
            o.x = pack2(A1[0] * w, A1[1] * w); o.y = pack2(A1[2] * w, A1[3] * w);
            o.z = pack2(A1[4] * w, A1[5] * w); o.w = pack2(A1[6] * w, A1[7] * w);
            *(uint4*)(aggb + (size_t)n1 * 64 + (sub << 2)) = o;
        }
    }
}

// ---------------- final: group-per-node (8 lanes), broadcast idx, no reduce ----------------

__global__ __launch_bounds__(256) void final_k(
        const int* __restrict__ rs, const int* __restrict__ deg,
        const ushort* __restrict__ csr16, const uint* __restrict__ t2,
        const uint* __restrict__ u2, const float* __restrict__ b2,
        const float* __restrict__ inv, float* __restrict__ out) {
    const int tid = threadIdx.x, lane = tid & 63, wid = tid >> 6;
    const int g = lane >> 3, sub = lane & 7;
    const int n = blockIdx.x * 32 + wid * 8 + g;
    if (n >= N_NODES) return;
    const int beg = rs[n], cnt = deg[n];
    float A[8] = {};
    const int nR = (cnt + 3) >> 2;
    #pragma unroll 4
    for (int r = 0; r < nR; ++r) {
        uint2 i2 = *(const uint2*)(csr16 + beg + (r << 2));     // 4 src ids, broadcast
        int s0 = i2.x & 0xFFFF, s1 = i2.x >> 16;
        int s2 = i2.y & 0xFFFF, s3 = i2.y >> 16;
        uint4 v0 = *(const uint4*)(t2 + (size_t)s0 * 32 + (sub << 2));
        uint4 v1 = *(const uint4*)(t2 + (size_t)s1 * 32 + (sub << 2));
        uint4 v2 = *(const uint4*)(t2 + (size_t)s2 * 32 + (sub << 2));
        uint4 v3 = *(const uint4*)(t2 + (size_t)s3 * 32 + (sub << 2));
        int e0 = r << 2;
        if (e0 + 0 < cnt) ACC8(A, v0);
        if (e0 + 1 < cnt) ACC8(A, v1);
        if (e0 + 2 < cnt) ACC8(A, v2);
        if (e0 + 3 < cnt) ACC8(A, v3);
    }
    const float w = inv[n];
    uint4 ur = *(const uint4*)(u2 + (size_t)n * 32 + (sub << 2));
    const float* br = b2 + (sub << 3);
    float4 o0, o1;
    o0.x = bflo(ur.x) + br[0] + A[0] * w;
    o0.y = bfhi(ur.x) + br[1] + A[1] * w;
    o0.z = bflo(ur.y) + br[2] + A[2] * w;
    o0.w = bfhi(ur.y) + br[3] + A[3] * w;
    o1.x = bflo(ur.z) + br[4] + A[4] * w;
    o1.y = bfhi(ur.z) + br[5] + A[5] * w;
    o1.z = bflo(ur.w) + br[6] + A[6] * w;
    o1.w = bfhi(ur.w) + br[7] + A[7] * w;
    float* orow = out + (size_t)n * 64 + (sub << 3);
    *(float4*)orow = o0;
    *(float4*)(orow + 4) = o1;
}

// ---------------- fused gemm12 (ping-pong BK=32 staging, single-stage phase-2 B) ----------------
// grid = 391, 512 threads = 8 waves. A-tile k<128 from aggb, k>=128 from xb.
// LDS: Hs[128][136] @0 (17408 ushorts); stage buffers SB0/SB1 @17408/+8192,
// each = A-panel[128][32] + B-panel[128][32]. Phase-1: sync; stage(p+1)->other
// buf; compute(p) — DMA overlaps MFMA. Phase-2 B2-half fills both buffers once.

#define HS_STRIDE 136
#define S_OFF 17408

__global__ __launch_bounds__(512) void gemm12_k(const ushort* __restrict__ aggb16,
                                                const ushort* __restrict__ xb16,
                                                const ushort* __restrict__ B1,
                                                const ushort* __restrict__ B2,
                                                const float* __restrict__ b1,
                                                ushort* __restrict__ t2,
                                                ushort* __restrict__ u2b) {
    __shared__ __align__(16) ushort lds[S_OFF + 16384];
    const int bm = blockIdx.x * 128;
    const int tid = threadIdx.x;
    const int w = tid >> 6, lane = tid & 63;
    const int q = lane >> 4, mr = lane & 15;
    const int wm = (w & 1) << 6;          // wave rows 0/64
    const int wn = (w >> 1) << 5;         // wave cols 0/32/64/96
    const int srow = tid >> 2;            // staging row 0..127
    const int scol = (tid & 3) << 3;      // ushort offset within 32-wide panel

    auto stage = [&](int h, int p, int buf) {
        const int k0 = p << 5;
        const ushort* Asrc = (k0 < 128)
            ? aggb16 + (size_t)(bm + srow) * 128 + k0
            : xb16 + (size_t)(bm + srow) * 128 + (k0 - 128);
        gload_lds16(Asrc + scol, lds + S_OFF + (buf << 13) + srow * 32 + scol);
        gload_lds16(B1 + (size_t)((h << 7) + srow) * 256 + k0 + scol,
                    lds + S_OFF + (buf << 13) + 4096 + srow * 32 + scol);
    };

    floatx4 acc2[4][2];
    #pragma unroll
    for (int i = 0; i < 4; ++i)
        #pragma unroll
        for (int j = 0; j < 2; ++j)
            acc2[i][j] = (floatx4){0.f, 0.f, 0.f, 0.f};

    #pragma unroll
    for (int h = 0; h < 2; ++h) {
        floatx4 acc1[4][2];
        #pragma unroll
        for (int i = 0; i < 4; ++i)
            #pragma unroll
            for (int j = 0; j < 2; ++j)
                acc1[i][j] = (floatx4){0.f, 0.f, 0.f, 0.f};
        stage(h, 0, 0);
        #pragma unroll
        for (int p = 0; p < 8; ++p) {
            __syncthreads();
            if (p < 7) stage(h, p + 1, (p + 1) & 1);
            const int buf = p & 1;
            short8 af[4], bfr[2];
            #pragma unroll
            for (int i = 0; i < 4; ++i)
                af[i] = *(const short8*)&lds[S_OFF + (buf << 13) + (wm + (i << 4) + mr) * 32 + (q << 3)];
            #pragma unroll
            for (int j = 0; j < 2; ++j)
                bfr[j] = *(const short8*)&lds[S_OFF + (buf << 13) + 4096 + (wn + (j << 4) + mr) * 32 + (q << 3)];
            #pragma unroll
            for (int i = 0; i < 4; ++i)
                #pragma unroll
                for (int j = 0; j < 2; ++j)
                    acc1[i][j] = __builtin_amdgcn_mfma_f32_16x16x32_bf16(af[i], bfr[j], acc1[i][j], 0, 0, 0);
        }
        __syncthreads();                      // stage bufs free for B2
        #pragma unroll
        for (int p2 = 0; p2 < 4; ++p2)        // B2 half fills both buffers (overlaps epilogue)
            gload_lds16(B2 + (size_t)srow * 256 + (h << 7) + (p2 << 5) + scol,
                        lds + S_OFF + (p2 << 12) + srow * 32 + scol);
        #pragma unroll
        for (int i = 0; i < 4; ++i) {         // epilogue 1: relu+bias -> Hs (bf16)
            int row = wm + (i << 4) + (q << 2);
            #pragma unroll
            for (int j = 0; j < 2; ++j) {
                int col = wn + (j << 4) + mr;
                float bv = b1[(h << 7) + col];
                #pragma unroll
                for (int r = 0; r < 4; ++r) {
                    float v = fmaxf(acc1[i][j][r] + bv, 0.f);
                    lds[(row + r) * HS_STRIDE + col] = f2bf(v);
                }
            }
        }
        __syncthreads();
        #pragma unroll
        for (int p2 = 0; p2 < 4; ++p2) {      // phase 2: acc2 += Hs @ B2half^T
            short8 af2[4], bf2[2];
            #pragma unroll
            for (int i = 0; i < 4; ++i)
                af2[i] = *(const short8*)&lds[(wm + (i << 4) + mr) * HS_STRIDE + (p2 << 5) + (q << 3)];
            #pragma unroll
            for (int j = 0; j < 2; ++j)
                bf2[j] = *(const short8*)&lds[S_OFF + (p2 << 12) + (wn + (j << 4) + mr) * 32 + (q << 3)];
            #pragma unroll
            for (int i = 0; i < 4; ++i)
                #pragma unroll
                for (int j = 0; j < 2; ++j)
                    acc2[i][j] = __builtin_amdgcn_mfma_f32_16x16x32_bf16(af2[i], bf2[j], acc2[i][j], 0, 0, 0);
        }
        __syncthreads();
    }
    #pragma unroll
    for (int i = 0; i < 4; ++i) {
        int row = bm + wm + (i << 4) + (q << 2);
        #pragma unroll
        for (int j = 0; j < 2; ++j) {
            int col = wn + (j << 4) + mr;
            #pragma unroll
            for (int r = 0; r < 4; ++r) {
                float v = acc2[i][j][r];
                if (col < 64) t2[(size_t)(row + r) * 64 + col] = f2bf(v);
                else          u2b[(size_t)(row + r) * 64 + (col - 64)] = f2bf(v);
            }
        }
    }
}

// ---------------- launch ----------------

extern "C" void kernel_launch(void* const* d_in, const int* in_sizes, int n_in,
                              void* d_out, int out_size, void* d_ws, size_t ws_size,
                              hipStream_t stream) {
    const float* x   = (const float*)d_in[0];
    const int*   ei  = (const int*)d_in[1];
    const float* W1l = (const float*)d_in[2];
    const float* W1r = (const float*)d_in[3];
    const float* b1  = (const float*)d_in[4];
    const float* W2l = (const float*)d_in[5];
    const float* W2r = (const float*)d_in[6];
    const float* b2  = (const float*)d_in[7];
    float* out = (float*)d_out;

    char* base = (char*)d_ws;
    size_t off = 0;
    auto alloc = [&](size_t bytes) -> void* {
        void* p = base + off;
        off = (off + bytes + 255) & ~(size_t)255;
        return p;
    };
    int*    deg        = (int*)alloc(M_PAD * 4);
    int*    rs         = (int*)alloc(M_PAD * 4);
    float*  inv        = (float*)alloc(M_PAD * 4);
    int*    bucket_cnt = (int*)alloc(K_BUCK * 4);
    ushort* csr16      = (ushort*)alloc((size_t)K_BUCK * CSR_SEG * 2);
    int*    part       = (int*)alloc((size_t)K_BUCK * BUCK_CAP * 4);
    uint*   xb         = (uint*)alloc((size_t)M_PAD * 64 * 4);   // bf16 [M_PAD][128]
    uint*   aggb       = (uint*)alloc((size_t)M_PAD * 64 * 4);   // bf16 [M_PAD][128]
    uint*   t2         = (uint*)alloc((size_t)M_PAD * 32 * 4);
    uint*   u2         = (uint*)alloc((size_t)M_PAD * 32 * 4);
    ushort* B1         = (ushort*)alloc(256 * 256 * 2);
    ushort* B2         = (ushort*)alloc(128 * 256 * 2);

    hipMemsetAsync(bucket_cnt, 0, K_BUCK * sizeof(int), stream);

    entry_k<<<P_BLOCKS + PREP_ELEMS / 256, 256, 0, stream>>>(
        ei, bucket_cnt, part, (const float2*)x, xb, W1l, W1r, W2l, W2r, B1, B2);

    buildagg_k<<<K_BUCK, 512, 0, stream>>>(part, bucket_cnt, rs, deg, inv,
                                           csr16, xb, aggb);

    gemm12_k<<<K_BUCK, 512, 0, stream>>>((const ushort*)aggb, (const ushort*)xb,
                                         B1, B2, b1, (ushort*)t2, (ushort*)u2);

    final_k<<<(N_NODES + 31) / 32, 256, 0, stream>>>(rs, deg, csr16, t2, u2, b2, inv, out);
}